// Round 1
// baseline (668.841 us; speedup 1.0000x reference)
//
#include <hip/hip_runtime.h>
#include <cstdint>

// Problem constants
#define B_    8
#define N_    1024
#define DIM_  768
#define H_    12
#define D_    64
#define SCALE_ 0.125f

typedef unsigned short u16;
typedef short bf16x8 __attribute__((ext_vector_type(8)));
typedef float f32x4  __attribute__((ext_vector_type(4)));

__device__ __forceinline__ u16 f2b(float f) {
  union { float f; unsigned u; } v; v.f = f;
  unsigned r = v.u + 0x7FFFu + ((v.u >> 16) & 1u);
  return (u16)(r >> 16);
}
__device__ __forceinline__ float b2f(u16 h) {
  union { unsigned u; float f; } v; v.u = ((unsigned)h) << 16; return v.f;
}
// async global->LDS, 16B per lane; LDS base must be wave-uniform (HW adds lane*16)
__device__ __forceinline__ void gl2lds16(const void* g, void* l) {
  __builtin_amdgcn_global_load_lds(
      (const __attribute__((address_space(1))) void*)g,
      (__attribute__((address_space(3))) void*)l, 16, 0, 0);
}

// ---------------------------------------------------------------- K0: fp32 -> bf16 casts
__global__ __launch_bounds__(256) void cast_all(
    const float4* __restrict__ s0, u16* __restrict__ d0, int n0,
    const float4* __restrict__ s1, u16* __restrict__ d1, int n1,
    const float4* __restrict__ s2, u16* __restrict__ d2, int n2,
    const float4* __restrict__ s3, u16* __restrict__ d3, int n3)
{
  int i = blockIdx.x * 256 + threadIdx.x;
  const float4* s; u16* d; int off;
  if (i < n0)               { s = s0; d = d0; off = i; }
  else if (i < n0+n1)       { s = s1; d = d1; off = i - n0; }
  else if (i < n0+n1+n2)    { s = s2; d = d2; off = i - n0 - n1; }
  else if (i < n0+n1+n2+n3) { s = s3; d = d3; off = i - n0 - n1 - n2; }
  else return;
  float4 v = s[off];
  ushort4 o; o.x = f2b(v.x); o.y = f2b(v.y); o.z = f2b(v.z); o.w = f2b(v.w);
  *(ushort4*)(d + (size_t)off * 4) = o;
}

// ---------------------------------------------------------------- K1: qv = x @ w_qv^T  (bf16 MFMA, m97 pattern)
// A [8192][768], W [1536][768]; C tile 128x128, BK=32; outputs q,v in [B,H,N,D] bf16
__global__ __launch_bounds__(256) void qv_gemm(
    const u16* __restrict__ A, const u16* __restrict__ W,
    u16* __restrict__ qo, u16* __restrict__ vo)
{
  __shared__ u16 As[128*32];
  __shared__ u16 Bs[128*32];
  const int tid = threadIdx.x, lane = tid & 63, wid = tid >> 6;
  const int m0 = blockIdx.y * 128, n0 = blockIdx.x * 128;
  const int wm = (wid >> 1) * 64, wn = (wid & 1) * 64;
  const int lr = lane & 15, lq = lane >> 4;
  f32x4 acc[4][4] = {};
  for (int k0 = 0; k0 < 768; k0 += 32) {
#pragma unroll
    for (int it = 0; it < 2; ++it) {
      int c = it * 256 + tid;
      int row = c >> 2, c8 = c & 3;
      gl2lds16(A + (size_t)(m0 + row) * 768 + k0 + c8 * 8, (char*)As + (it*256 + wid*64) * 16);
      gl2lds16(W + (size_t)(n0 + row) * 768 + k0 + c8 * 8, (char*)Bs + (it*256 + wid*64) * 16);
    }
    __syncthreads();
    bf16x8 af[4], bfr[4];
#pragma unroll
    for (int i = 0; i < 4; ++i) {
      af[i]  = *(const bf16x8*)&As[(wm + i*16 + lr) * 32 + lq * 8];
      bfr[i] = *(const bf16x8*)&Bs[(wn + i*16 + lr) * 32 + lq * 8];
    }
#pragma unroll
    for (int mi = 0; mi < 4; ++mi)
#pragma unroll
      for (int nj = 0; nj < 4; ++nj)
        acc[mi][nj] = __builtin_amdgcn_mfma_f32_16x16x32_bf16(af[mi], bfr[nj], acc[mi][nj], 0, 0, 0);
    __syncthreads();
  }
  // epilogue: C/D layout col=lane&15, row=(lane>>4)*4+reg (m89-verified)
#pragma unroll
  for (int mi = 0; mi < 4; ++mi)
#pragma unroll
    for (int nj = 0; nj < 4; ++nj)
#pragma unroll
      for (int r = 0; r < 4; ++r) {
        int row = m0 + wm + mi*16 + lq*4 + r;   // flat b*N+n
        int col = n0 + wn + nj*16 + lr;         // e in [0,1536)
        u16 bv = f2b(acc[mi][nj][r]);
        int b = row >> 10, n = row & 1023;
        if (col < 768) { int h = col >> 6, d = col & 63;
          qo[(((size_t)(b*12 + h)) << 16) + (n << 6) + d] = bv;
        } else { int e = col - 768; int h = e >> 6, d = e & 63;
          vo[(((size_t)(b*12 + h)) << 16) + (n << 6) + d] = bv;
        }
      }
}

// ---------------------------------------------------------------- K1b: v [BH][1024][64] -> vT [BH][64][1024]
__global__ __launch_bounds__(256) void transpose_v(const u16* __restrict__ v, u16* __restrict__ vt)
{
  __shared__ u16 t[64][65];
  int bh = blockIdx.y, n0 = blockIdx.x * 64, tid = threadIdx.x;
  const u16* src = v + (((size_t)bh) << 16) + (size_t)n0 * 64;
  u16* dst = vt + (((size_t)bh) << 16) + n0;
#pragma unroll
  for (int i = 0; i < 16; ++i) {
    int e = i*256 + tid; t[e >> 6][e & 63] = src[e];
  }
  __syncthreads();
#pragma unroll
  for (int i = 0; i < 16; ++i) {
    int e = i*256 + tid; int d = e >> 6, r = e & 63;
    dst[(size_t)d * 1024 + r] = t[r][d];
  }
}

// ---------------------------------------------------------------- K3: qs[h,n,d] = sum_b q
__global__ __launch_bounds__(256) void qs_kernel(const u16* __restrict__ q, float* __restrict__ qs)
{
  int idx = blockIdx.x * 256 + threadIdx.x;   // 12*1024*64
  int h = idx >> 16, rem = idx & 65535;
  float s = 0.f;
#pragma unroll
  for (int b = 0; b < 8; ++b) s += b2f(q[(((size_t)(b*12 + h)) << 16) + rem]);
  qs[idx] = s;
}

// ---------------------------------------------------------------- K2/K4: 64x64 Gram matrices (atomic accumulate)
__global__ __launch_bounds__(256) void gram_kernel(
    const u16* __restrict__ src, float* __restrict__ gram, int rows_per_block, int b_interleaved)
{
  __shared__ float t[64*68];
  int h = blockIdx.y, r0 = blockIdx.x * rows_per_block, tid = threadIdx.x;
  int ci = tid >> 2, cjs = (tid & 3) * 16;
  float a[16];
#pragma unroll
  for (int j = 0; j < 16; ++j) a[j] = 0.f;
  for (int t0 = 0; t0 < rows_per_block; t0 += 64) {
#pragma unroll
    for (int i = 0; i < 16; ++i) {
      int e = i*256 + tid; int r = e >> 6, d = e & 63; int gr = r0 + t0 + r;
      size_t addr;
      if (b_interleaved) { int b = gr >> 10, n = gr & 1023; addr = (((size_t)(b*12 + h)) << 16) + (n << 6) + d; }
      else addr = (((size_t)h) << 16) + ((size_t)gr << 6) + d;
      t[r*68 + d] = b2f(src[addr]);
    }
    __syncthreads();
    for (int m = 0; m < 64; ++m) {
      float ki = t[m*68 + ci];
#pragma unroll
      for (int j = 0; j < 16; ++j) a[j] += ki * t[m*68 + cjs + j];
    }
    __syncthreads();
  }
  float* g = gram + h*4096 + ci*64 + cjs;
#pragma unroll
  for (int j = 0; j < 16; ++j) atomicAdd(g + j, a[j]);
}

// ---------------------------------------------------------------- K2b: bias sums + cross term (one 50MB pass)
// acc layout: [0..11]=Sb, [12..23]=Sb2, [24..35]=Cross
__global__ __launch_bounds__(256) void bias_stats(
    const float* __restrict__ bias, const float* __restrict__ k,
    const float* __restrict__ qs, float* __restrict__ acc)
{
  __shared__ float kt[64*68];
  __shared__ float bt[32*64];
  __shared__ float red[12];
  int h = blockIdx.y, n0 = blockIdx.x * 32;
  int tid = threadIdx.x, lane = tid & 63, wid = tid >> 6;
  int d = tid & 63, rg = tid >> 6;
  float kb[8];
#pragma unroll
  for (int j = 0; j < 8; ++j) kb[j] = 0.f;
  float sb = 0.f, sb2 = 0.f;
  for (int m0 = 0; m0 < 1024; m0 += 64) {
    __syncthreads();
#pragma unroll
    for (int i = 0; i < 4; ++i) {            // k tile 64x64 fp32
      int f = i*256 + tid; int r = f >> 4, c4 = (f & 15) * 4;
      float4 kv = *(const float4*)(k + (((size_t)h) << 16) + (size_t)(m0 + r) * 64 + c4);
      *(float4*)&kt[r*68 + c4] = kv;
    }
#pragma unroll
    for (int i = 0; i < 2; ++i) {            // bias tile 32x64 fp32
      int f = i*256 + tid; int r = f >> 4, c4 = (f & 15) * 4;
      float4 bv = *(const float4*)(bias + (((size_t)h) << 20) + (size_t)(n0 + r) * 1024 + m0 + c4);
      *(float4*)&bt[r*64 + c4] = bv;
      sb  += bv.x + bv.y + bv.z + bv.w;
      sb2 += bv.x*bv.x + bv.y*bv.y + bv.z*bv.z + bv.w*bv.w;
    }
    __syncthreads();
    for (int m = 0; m < 64; ++m) {
      float kv = kt[m*68 + d];
#pragma unroll
      for (int j = 0; j < 8; ++j) kb[j] += bt[(rg + 4*j)*64 + m] * kv;
    }
  }
  float cross = 0.f;
#pragma unroll
  for (int j = 0; j < 8; ++j)
    cross += kb[j] * qs[(((size_t)h) << 16) + (size_t)(n0 + rg + 4*j) * 64 + d];
#pragma unroll
  for (int s = 32; s; s >>= 1) {
    sb += __shfl_xor(sb, s); sb2 += __shfl_xor(sb2, s); cross += __shfl_xor(cross, s);
  }
  if (lane == 0) { red[wid] = sb; red[4 + wid] = sb2; red[8 + wid] = cross; }
  __syncthreads();
  if (tid == 0) {
    atomicAdd(acc + h,      red[0] + red[1] + red[2] + red[3]);
    atomicAdd(acc + 12 + h, red[4] + red[5] + red[6] + red[7]);
    atomicAdd(acc + 24 + h, red[8] + red[9] + red[10] + red[11]);
  }
}

// ---------------------------------------------------------------- K4b: qsum/ksum per head
__global__ void sums_kernel(const float* __restrict__ qs, const u16* __restrict__ kb16,
                            float* __restrict__ qsum, float* __restrict__ ksum)
{
  int h = blockIdx.x, d = threadIdx.x;  // 64 threads
  float s1 = 0.f, s2 = 0.f;
  for (int n = 0; n < 1024; ++n) {
    s1 += qs[(((size_t)h) << 16) + (n << 6) + d];
    s2 += b2f(kb16[(((size_t)h) << 16) + (n << 6) + d]);
  }
  qsum[h*64 + d] = s1; ksum[h*64 + d] = s2;
}

// ---------------------------------------------------------------- K5: assemble var -> temp[h] = gamma*SCALE*rsqrt(var+eps)
__global__ void finalize_kernel(const float* __restrict__ qsum, const float* __restrict__ ksum,
                                const float* __restrict__ Qg, const float* __restrict__ Kg,
                                const float* __restrict__ acc, const float* __restrict__ gamma,
                                float* __restrict__ temp)
{
  int h = blockIdx.x, t = threadIdx.x;  // 64 threads = 1 wave
  float s1 = qsum[h*64 + t] * ksum[h*64 + t];
  float s2 = 0.f;
  for (int c = 0; c < 64; ++c) s2 += Qg[h*4096 + t*64 + c] * Kg[h*4096 + t*64 + c];
#pragma unroll
  for (int s = 32; s; s >>= 1) { s1 += __shfl_xor(s1, s); s2 += __shfl_xor(s2, s); }
  if (t == 0) {
    double M = 8388608.0;  // B*N*N
    double Sb = acc[h], Sb2 = acc[12 + h], Cross = acc[24 + h];
    double Eraw  = ((double)s1 + 8.0 * Sb) / M;
    double Eraw2 = ((double)s2 + 2.0 * Cross + 8.0 * Sb2) / M;
    double var = (double)SCALE_ * (double)SCALE_ * (Eraw2 - Eraw * Eraw);
    double rstd = 1.0 / sqrt(var + 1e-5);
    temp[h] = (float)((double)gamma[h] * (double)SCALE_ * rstd);
  }
}

// ---------------------------------------------------------------- K6: fused flash attention (64 q-rows, 64-key tiles)
// logits = (q.k + bias) * temp[h]; online softmax; O = P@V; out bf16 [B,N,768]
__global__ __launch_bounds__(256) void attn_kernel(
    const u16* __restrict__ q, const u16* __restrict__ k, const u16* __restrict__ vT,
    const float* __restrict__ bias, const float* __restrict__ temp, u16* __restrict__ out)
{
  extern __shared__ char smem[];
  u16*  qt = (u16*)smem;              // [2][64][32] bf16, split-k halves (bank-optimal)
  u16*  kt = qt + 4096;               // [2][64][32]
  u16*  vt = kt + 4096;               // [2 m-half][64 d][32 m]
  float* bl = (float*)(vt + 4096);    // [64 n][64 m] fp32
  u16*  pt = (u16*)(bl + 4096);       // [64][72] bf16 (+8 pad for banks)
  const int tid = threadIdx.x, lane = tid & 63, wid = tid >> 6;
  const int lr = lane & 15, lq = lane >> 4;
  const int n0 = blockIdx.x * 64, h = blockIdx.y, b = blockIdx.z;
  const size_t qbase = ((((size_t)b) * 12 + h) << 16) + ((size_t)n0 << 6);
  const size_t kbase = ((size_t)h) << 16;
  const size_t vbase = ((((size_t)b) * 12 + h) << 16);
  const size_t bbase = (((size_t)h) << 20) + ((size_t)n0 << 10);
  const float tmp = temp[h];

#pragma unroll
  for (int it = 0; it < 2; ++it) {    // q tile once
    int c = it*256 + tid; int ks = c >> 8, r = (c >> 2) & 63, c8 = c & 3;
    gl2lds16(q + qbase + (size_t)r * 64 + ks*32 + c8*8, (char*)qt + (it*256 + wid*64) * 16);
  }
  float mrun[4], lrun[4];
  f32x4 oacc[4] = {};
#pragma unroll
  for (int r = 0; r < 4; ++r) { mrun[r] = -3.0e38f; lrun[r] = 0.f; }

  for (int m0 = 0; m0 < 1024; m0 += 64) {
#pragma unroll
    for (int it = 0; it < 2; ++it) {
      int c = it*256 + tid; int ks = c >> 8, r = (c >> 2) & 63, c8 = c & 3;
      gl2lds16(k  + kbase + (size_t)(m0 + r) * 64 + ks*32 + c8*8, (char*)kt + (it*256 + wid*64) * 16);
      gl2lds16(vT + vbase + (size_t)r * 1024 + m0 + ks*32 + c8*8, (char*)vt + (it*256 + wid*64) * 16);
    }
#pragma unroll
    for (int it = 0; it < 4; ++it) {
      int c = it*256 + tid; int r = c >> 4, c4 = c & 15;
      gl2lds16(bias + bbase + (size_t)r * 1024 + m0 + c4*4, (char*)bl + (it*256 + wid*64) * 16);
    }
    __syncthreads();
    // S = q @ k^T  (wave owns 16 q-rows x 64 keys)
    f32x4 s[4] = {};
#pragma unroll
    for (int ks = 0; ks < 2; ++ks) {
      bf16x8 aq = *(const bf16x8*)&qt[ks*2048 + (wid*16 + lr)*32 + lq*8];
#pragma unroll
      for (int nj = 0; nj < 4; ++nj) {
        bf16x8 bk = *(const bf16x8*)&kt[ks*2048 + (nj*16 + lr)*32 + lq*8];
        s[nj] = __builtin_amdgcn_mfma_f32_16x16x32_bf16(aq, bk, s[nj], 0, 0, 0);
      }
    }
    // online softmax (rows live across the 16 lanes of a quad)
    int rowl = wid*16 + lq*4;
#pragma unroll
    for (int r = 0; r < 4; ++r) {
      float lg[4];
#pragma unroll
      for (int nj = 0; nj < 4; ++nj)
        lg[nj] = (s[nj][r] + bl[(rowl + r)*64 + nj*16 + lr]) * tmp;
      float mx = fmaxf(fmaxf(lg[0], lg[1]), fmaxf(lg[2], lg[3]));
#pragma unroll
      for (int sh = 1; sh < 16; sh <<= 1) mx = fmaxf(mx, __shfl_xor(mx, sh));
      float mnew = fmaxf(mrun[r], mx);
      float alpha = __expf(mrun[r] - mnew);
      float ps = 0.f;
#pragma unroll
      for (int nj = 0; nj < 4; ++nj) {
        float p = __expf(lg[nj] - mnew);
        ps += p;
        pt[(rowl + r)*72 + nj*16 + lr] = f2b(p);
      }
#pragma unroll
      for (int sh = 1; sh < 16; sh <<= 1) ps += __shfl_xor(ps, sh);
      lrun[r] = lrun[r] * alpha + ps;
      mrun[r] = mnew;
#pragma unroll
      for (int dj = 0; dj < 4; ++dj) oacc[dj][r] *= alpha;
    }
    // O += P @ V   (A = P from own wave's pt rows; B^T = vT tile)
#pragma unroll
    for (int ks = 0; ks < 2; ++ks) {
      bf16x8 ap = *(const bf16x8*)&pt[(wid*16 + lr)*72 + ks*32 + lq*8];
#pragma unroll
      for (int dj = 0; dj < 4; ++dj) {
        bf16x8 bv = *(const bf16x8*)&vt[ks*2048 + (dj*16 + lr)*32 + lq*8];
        oacc[dj] = __builtin_amdgcn_mfma_f32_16x16x32_bf16(ap, bv, oacc[dj], 0, 0, 0);
      }
    }
    __syncthreads();
  }
#pragma unroll
  for (int dj = 0; dj < 4; ++dj)
#pragma unroll
    for (int r = 0; r < 4; ++r) {
      int n = n0 + wid*16 + lq*4 + r;
      int col = h*64 + dj*16 + lr;
      out[((size_t)(b*1024 + n)) * 768 + col] = f2b(oacc[dj][r] / lrun[r]);
    }
}

// ---------------------------------------------------------------- K7: out = attn @ w_proj^T + b_proj (fp32 out)
__global__ __launch_bounds__(256) void proj_gemm(
    const u16* __restrict__ A, const u16* __restrict__ W,
    const float* __restrict__ bp, float* __restrict__ out)
{
  __shared__ u16 As[128*32];
  __shared__ u16 Bs[128*32];
  const int tid = threadIdx.x, lane = tid & 63, wid = tid >> 6;
  const int m0 = blockIdx.y * 128, n0 = blockIdx.x * 128;
  const int wm = (wid >> 1) * 64, wn = (wid & 1) * 64;
  const int lr = lane & 15, lq = lane >> 4;
  f32x4 acc[4][4] = {};
  for (int k0 = 0; k0 < 768; k0 += 32) {
#pragma unroll
    for (int it = 0; it < 2; ++it) {
      int c = it*256 + tid; int row = c >> 2, c8 = c & 3;
      gl2lds16(A + (size_t)(m0 + row) * 768 + k0 + c8*8, (char*)As + (it*256 + wid*64) * 16);
      gl2lds16(W + (size_t)(n0 + row) * 768 + k0 + c8*8, (char*)Bs + (it*256 + wid*64) * 16);
    }
    __syncthreads();
    bf16x8 af[4], bfr[4];
#pragma unroll
    for (int i = 0; i < 4; ++i) {
      af[i]  = *(const bf16x8*)&As[(wm + i*16 + lr)*32 + lq*8];
      bfr[i] = *(const bf16x8*)&Bs[(wn + i*16 + lr)*32 + lq*8];
    }
#pragma unroll
    for (int mi = 0; mi < 4; ++mi)
#pragma unroll
      for (int nj = 0; nj < 4; ++nj)
        acc[mi][nj] = __builtin_amdgcn_mfma_f32_16x16x32_bf16(af[mi], bfr[nj], acc[mi][nj], 0, 0, 0);
    __syncthreads();
  }
#pragma unroll
  for (int mi = 0; mi < 4; ++mi)
#pragma unroll
    for (int nj = 0; nj < 4; ++nj)
#pragma unroll
      for (int r = 0; r < 4; ++r) {
        int row = m0 + wm + mi*16 + lq*4 + r;
        int col = n0 + wn + nj*16 + lr;
        out[(size_t)row * 768 + col] = acc[mi][nj][r] + bp[col];
      }
}

// ----------------------------------------------------------------
extern "C" void kernel_launch(void* const* d_in, const int* in_sizes, int n_in,
                              void* d_out, int out_size, void* d_ws, size_t ws_size,
                              hipStream_t stream)
{
  const float* x     = (const float*)d_in[0];
  const float* wqv   = (const float*)d_in[1];
  const float* ek    = (const float*)d_in[2];
  const float* ebias = (const float*)d_in[3];
  const float* gamma = (const float*)d_in[4];
  // d_in[5] = bn_beta: cancels inside softmax (per-row constant) — unused.
  const float* wp    = (const float*)d_in[6];
  const float* bp    = (const float*)d_in[7];
  float* out = (float*)d_out;

  char* ws = (char*)d_ws;
  size_t off = 0;
  auto alloc = [&](size_t bytes) { char* p = ws + off; off += (bytes + 255) & ~(size_t)255; return p; };
  u16* x16   = (u16*)alloc((size_t)8192*768*2);
  u16* wqv16 = (u16*)alloc((size_t)1536*768*2);
  u16* wp16  = (u16*)alloc((size_t)768*768*2);
  u16* k16   = (u16*)alloc((size_t)12*1024*64*2);
  u16* q16   = (u16*)alloc((size_t)8*12*1024*64*2);
  u16* v16   = (u16*)alloc((size_t)8*12*1024*64*2);
  u16* vt16  = (u16*)alloc((size_t)8*12*1024*64*2);
  float* qs  = (float*)alloc((size_t)12*1024*64*4);
  float* acc = (float*)alloc(3*12*4);           // zero-region start
  float* Kg  = (float*)alloc((size_t)12*4096*4);
  float* Qg  = (float*)alloc((size_t)12*4096*4);
  size_t zbytes = (size_t)(((char*)Qg + (size_t)12*4096*4) - (char*)acc);
  float* qsum = (float*)alloc(12*64*4);
  float* ksum = (float*)alloc(12*64*4);
  float* temp = (float*)alloc(12*4);
  u16* attn16 = x16;  // reuse: x16 dead after qv_gemm

  hipMemsetAsync(acc, 0, zbytes, stream);

  { // K0: casts (x, w_qv, w_proj, ext_k)
    int c0 = 8192*768/4, c1 = 1536*768/4, c2 = 768*768/4, c3 = 12*1024*64/4;
    int total = c0 + c1 + c2 + c3;
    cast_all<<<(total + 255)/256, 256, 0, stream>>>(
        (const float4*)x, x16, c0, (const float4*)wqv, wqv16, c1,
        (const float4*)wp, wp16, c2, (const float4*)ek, k16, c3);
  }
  qv_gemm<<<dim3(12, 64), 256, 0, stream>>>(x16, wqv16, q16, v16);
  transpose_v<<<dim3(16, 96), 256, 0, stream>>>(v16, vt16);
  qs_kernel<<<3072, 256, 0, stream>>>(q16, qs);
  gram_kernel<<<dim3(8, 12), 256, 0, stream>>>(k16, Kg, 128, 0);
  gram_kernel<<<dim3(64, 12), 256, 0, stream>>>(q16, Qg, 128, 1);
  bias_stats<<<dim3(32, 12), 256, 0, stream>>>(ebias, ek, qs, acc);
  sums_kernel<<<12, 64, 0, stream>>>(qs, k16, qsum, ksum);
  finalize_kernel<<<12, 64, 0, stream>>>(qsum, ksum, Qg, Kg, acc, gamma, temp);
  attn_kernel<<<dim3(16, 12, 8), 256, 50176, stream>>>(q16, k16, vt16, ebias, temp, attn16);
  proj_gemm<<<dim3(6, 64), 256, 0, stream>>>(attn16, wp16, bp, out);
}

// Round 2
// 463.243 us; speedup vs baseline: 1.4438x; 1.4438x over previous
//
#include <hip/hip_runtime.h>
#include <cstdint>

// Problem constants
#define B_    8
#define N_    1024
#define DIM_  768
#define H_    12
#define D_    64
#define SCALE_ 0.125f
#define GQ_   32   // partial-gram blocks per head for Q (8192 rows / 256)
#define GK_   4    // partial-gram blocks per head for K (1024 rows / 256)

typedef unsigned short u16;
typedef short bf16x8 __attribute__((ext_vector_type(8)));
typedef float f32x4  __attribute__((ext_vector_type(4)));

__device__ __forceinline__ u16 f2b(float f) {
  union { float f; unsigned u; } v; v.f = f;
  unsigned r = v.u + 0x7FFFu + ((v.u >> 16) & 1u);
  return (u16)(r >> 16);
}
__device__ __forceinline__ float b2f(u16 h) {
  union { unsigned u; float f; } v; v.u = ((unsigned)h) << 16; return v.f;
}
// async global->LDS, 16B per lane; LDS base must be wave-uniform (HW adds lane*16)
__device__ __forceinline__ void gl2lds16(const void* g, void* l) {
  __builtin_amdgcn_global_load_lds(
      (const __attribute__((address_space(1))) void*)g,
      (__attribute__((address_space(3))) void*)l, 16, 0, 0);
}

// ---------------------------------------------------------------- K0: fp32 -> bf16 casts
__global__ __launch_bounds__(256) void cast_all(
    const float4* __restrict__ s0, u16* __restrict__ d0, int n0,
    const float4* __restrict__ s1, u16* __restrict__ d1, int n1,
    const float4* __restrict__ s2, u16* __restrict__ d2, int n2,
    const float4* __restrict__ s3, u16* __restrict__ d3, int n3)
{
  int i = blockIdx.x * 256 + threadIdx.x;
  const float4* s; u16* d; int off;
  if (i < n0)               { s = s0; d = d0; off = i; }
  else if (i < n0+n1)       { s = s1; d = d1; off = i - n0; }
  else if (i < n0+n1+n2)    { s = s2; d = d2; off = i - n0 - n1; }
  else if (i < n0+n1+n2+n3) { s = s3; d = d3; off = i - n0 - n1 - n2; }
  else return;
  float4 v = s[off];
  ushort4 o; o.x = f2b(v.x); o.y = f2b(v.y); o.z = f2b(v.z); o.w = f2b(v.w);
  *(ushort4*)(d + (size_t)off * 4) = o;
}

// ---------------------------------------------------------------- K1: qv = x @ w_qv^T  (bf16 MFMA, m97 pattern)
__global__ __launch_bounds__(256) void qv_gemm(
    const u16* __restrict__ A, const u16* __restrict__ W,
    u16* __restrict__ qo, u16* __restrict__ vo)
{
  __shared__ u16 As[128*32];
  __shared__ u16 Bs[128*32];
  const int tid = threadIdx.x, lane = tid & 63, wid = tid >> 6;
  const int m0 = blockIdx.y * 128, n0 = blockIdx.x * 128;
  const int wm = (wid >> 1) * 64, wn = (wid & 1) * 64;
  const int lr = lane & 15, lq = lane >> 4;
  f32x4 acc[4][4] = {};
  for (int k0 = 0; k0 < 768; k0 += 32) {
#pragma unroll
    for (int it = 0; it < 2; ++it) {
      int c = it * 256 + tid;
      int row = c >> 2, c8 = c & 3;
      gl2lds16(A + (size_t)(m0 + row) * 768 + k0 + c8 * 8, (char*)As + (it*256 + wid*64) * 16);
      gl2lds16(W + (size_t)(n0 + row) * 768 + k0 + c8 * 8, (char*)Bs + (it*256 + wid*64) * 16);
    }
    __syncthreads();
    bf16x8 af[4], bfr[4];
#pragma unroll
    for (int i = 0; i < 4; ++i) {
      af[i]  = *(const bf16x8*)&As[(wm + i*16 + lr) * 32 + lq * 8];
      bfr[i] = *(const bf16x8*)&Bs[(wn + i*16 + lr) * 32 + lq * 8];
    }
#pragma unroll
    for (int mi = 0; mi < 4; ++mi)
#pragma unroll
      for (int nj = 0; nj < 4; ++nj)
        acc[mi][nj] = __builtin_amdgcn_mfma_f32_16x16x32_bf16(af[mi], bfr[nj], acc[mi][nj], 0, 0, 0);
    __syncthreads();
  }
#pragma unroll
  for (int mi = 0; mi < 4; ++mi)
#pragma unroll
    for (int nj = 0; nj < 4; ++nj)
#pragma unroll
      for (int r = 0; r < 4; ++r) {
        int row = m0 + wm + mi*16 + lq*4 + r;   // flat b*N+n
        int col = n0 + wn + nj*16 + lr;         // e in [0,1536)
        u16 bv = f2b(acc[mi][nj][r]);
        int b = row >> 10, n = row & 1023;
        if (col < 768) { int h = col >> 6, d = col & 63;
          qo[(((size_t)(b*12 + h)) << 16) + (n << 6) + d] = bv;
        } else { int e = col - 768; int h = e >> 6, d = e & 63;
          vo[(((size_t)(b*12 + h)) << 16) + (n << 6) + d] = bv;
        }
      }
}

// ---------------------------------------------------------------- K1b: v [BH][1024][64] -> vT [BH][64][1024]
__global__ __launch_bounds__(256) void transpose_v(const u16* __restrict__ v, u16* __restrict__ vt)
{
  __shared__ u16 t[64][65];
  int bh = blockIdx.y, n0 = blockIdx.x * 64, tid = threadIdx.x;
  const u16* src = v + (((size_t)bh) << 16) + (size_t)n0 * 64;
  u16* dst = vt + (((size_t)bh) << 16) + n0;
#pragma unroll
  for (int i = 0; i < 16; ++i) {
    int e = i*256 + tid; t[e >> 6][e & 63] = src[e];
  }
  __syncthreads();
#pragma unroll
  for (int i = 0; i < 16; ++i) {
    int e = i*256 + tid; int d = e >> 6, r = e & 63;
    dst[(size_t)d * 1024 + r] = t[r][d];
  }
}

// ---------------------------------------------------------------- K3: qs[h,n,d] = sum_b q
__global__ __launch_bounds__(256) void qs_kernel(const u16* __restrict__ q, float* __restrict__ qs)
{
  int idx = blockIdx.x * 256 + threadIdx.x;   // 12*1024*64
  int h = idx >> 16, rem = idx & 65535;
  float s = 0.f;
#pragma unroll
  for (int b = 0; b < 8; ++b) s += b2f(q[(((size_t)(b*12 + h)) << 16) + rem]);
  qs[idx] = s;
}

// ---------------------------------------------------------------- K2/K4: 64x64 Gram partials (NO atomics)
// Each block computes a private 64x64 partial gram over rows_per_block rows,
// writes to gpart[(blockIdx.x*12 + h)*4096]. 4x4 per-thread tile:
// 2x ds_read_b128 per 16 FMA (was 5 reads/16 FMA + 3.1M device atomics).
__global__ __launch_bounds__(256) void gram_kernel(
    const u16* __restrict__ src, float* __restrict__ gpart,
    int rows_per_block, int b_interleaved)
{
  __shared__ float t[64*68];
  const int h = blockIdx.y, r0 = blockIdx.x * rows_per_block, tid = threadIdx.x;
  const int rr = (tid >> 4) * 4;   // row base 0..60
  const int cc = (tid & 15) * 4;   // col base 0..60
  float a[4][4] = {{0.f}};
  for (int t0 = 0; t0 < rows_per_block; t0 += 64) {
#pragma unroll
    for (int i = 0; i < 4; ++i) {
      int e = i*256 + tid;               // 0..1023 -> 64 rows x 16 ushort4
      int r = e >> 4, d4 = (e & 15) * 4;
      int gr = r0 + t0 + r;
      size_t addr;
      if (b_interleaved) { int b = gr >> 10, n = gr & 1023;
        addr = (((size_t)(b*12 + h)) << 16) + (n << 6) + d4; }
      else addr = (((size_t)h) << 16) + ((size_t)gr << 6) + d4;
      ushort4 u = *(const ushort4*)(src + addr);
      float4 f; f.x = b2f(u.x); f.y = b2f(u.y); f.z = b2f(u.z); f.w = b2f(u.w);
      *(float4*)&t[r*68 + d4] = f;
    }
    __syncthreads();
#pragma unroll 4
    for (int m = 0; m < 64; ++m) {
      float4 rv = *(const float4*)&t[m*68 + rr];
      float4 cv = *(const float4*)&t[m*68 + cc];
      a[0][0] += rv.x*cv.x; a[0][1] += rv.x*cv.y; a[0][2] += rv.x*cv.z; a[0][3] += rv.x*cv.w;
      a[1][0] += rv.y*cv.x; a[1][1] += rv.y*cv.y; a[1][2] += rv.y*cv.z; a[1][3] += rv.y*cv.w;
      a[2][0] += rv.z*cv.x; a[2][1] += rv.z*cv.y; a[2][2] += rv.z*cv.z; a[2][3] += rv.z*cv.w;
      a[3][0] += rv.w*cv.x; a[3][1] += rv.w*cv.y; a[3][2] += rv.w*cv.z; a[3][3] += rv.w*cv.w;
    }
    __syncthreads();
  }
  float* g = gpart + (((size_t)blockIdx.x) * 12 + h) * 4096;
#pragma unroll
  for (int i = 0; i < 4; ++i)
    *(float4*)&g[(rr + i)*64 + cc] = make_float4(a[i][0], a[i][1], a[i][2], a[i][3]);
}

// ---------------------------------------------------------------- K2b: bias sums + cross term (one 50MB pass)
// acc layout: [0..11]=Sb, [12..23]=Sb2, [24..35]=Cross
__global__ __launch_bounds__(256) void bias_stats(
    const float* __restrict__ bias, const float* __restrict__ k,
    const float* __restrict__ qs, float* __restrict__ acc)
{
  __shared__ float kt[64*68];
  __shared__ float bt[32*64];
  __shared__ float red[12];
  int h = blockIdx.y, n0 = blockIdx.x * 32;
  int tid = threadIdx.x, lane = tid & 63, wid = tid >> 6;
  int d = tid & 63, rg = tid >> 6;
  float kb[8];
#pragma unroll
  for (int j = 0; j < 8; ++j) kb[j] = 0.f;
  float sb = 0.f, sb2 = 0.f;
  for (int m0 = 0; m0 < 1024; m0 += 64) {
    __syncthreads();
#pragma unroll
    for (int i = 0; i < 4; ++i) {            // k tile 64x64 fp32
      int f = i*256 + tid; int r = f >> 4, c4 = (f & 15) * 4;
      float4 kv = *(const float4*)(k + (((size_t)h) << 16) + (size_t)(m0 + r) * 64 + c4);
      *(float4*)&kt[r*68 + c4] = kv;
    }
#pragma unroll
    for (int i = 0; i < 2; ++i) {            // bias tile 32x64 fp32
      int f = i*256 + tid; int r = f >> 4, c4 = (f & 15) * 4;
      float4 bv = *(const float4*)(bias + (((size_t)h) << 20) + (size_t)(n0 + r) * 1024 + m0 + c4);
      *(float4*)&bt[r*64 + c4] = bv;
      sb  += bv.x + bv.y + bv.z + bv.w;
      sb2 += bv.x*bv.x + bv.y*bv.y + bv.z*bv.z + bv.w*bv.w;
    }
    __syncthreads();
    for (int m = 0; m < 64; ++m) {
      float kv = kt[m*68 + d];
#pragma unroll
      for (int j = 0; j < 8; ++j) kb[j] += bt[(rg + 4*j)*64 + m] * kv;
    }
  }
  float cross = 0.f;
#pragma unroll
  for (int j = 0; j < 8; ++j)
    cross += kb[j] * qs[(((size_t)h) << 16) + (size_t)(n0 + rg + 4*j) * 64 + d];
#pragma unroll
  for (int s = 32; s; s >>= 1) {
    sb += __shfl_xor(sb, s); sb2 += __shfl_xor(sb2, s); cross += __shfl_xor(cross, s);
  }
  if (lane == 0) { red[wid] = sb; red[4 + wid] = sb2; red[8 + wid] = cross; }
  __syncthreads();
  if (tid == 0) {
    atomicAdd(acc + h,      red[0] + red[1] + red[2] + red[3]);
    atomicAdd(acc + 12 + h, red[4] + red[5] + red[6] + red[7]);
    atomicAdd(acc + 24 + h, red[8] + red[9] + red[10] + red[11]);
  }
}

// ---------------------------------------------------------------- K4b: qsum/ksum per head
__global__ void sums_kernel(const float* __restrict__ qs, const u16* __restrict__ kb16,
                            float* __restrict__ qsum, float* __restrict__ ksum)
{
  int h = blockIdx.x, d = threadIdx.x;  // 64 threads
  float s1 = 0.f, s2 = 0.f;
  for (int n = 0; n < 1024; ++n) {
    s1 += qs[(((size_t)h) << 16) + (n << 6) + d];
    s2 += b2f(kb16[(((size_t)h) << 16) + (n << 6) + d]);
  }
  qsum[h*64 + d] = s1; ksum[h*64 + d] = s2;
}

// ---------------------------------------------------------------- K5: reduce gram partials + assemble var -> temp[h]
__global__ __launch_bounds__(256) void finalize_kernel(
    const float* __restrict__ qsum, const float* __restrict__ ksum,
    const float* __restrict__ Qgp, const float* __restrict__ Kgp,
    const float* __restrict__ acc, const float* __restrict__ gamma,
    float* __restrict__ temp)
{
  __shared__ float qg[4096];
  __shared__ float kg[4096];
  __shared__ float red[8];
  int h = blockIdx.x, tid = threadIdx.x, wid = tid >> 6, lane = tid & 63;
#pragma unroll
  for (int i = 0; i < 16; ++i) {
    int e = i*256 + tid;
    float q = 0.f, k = 0.f;
    for (int g = 0; g < GQ_; ++g) q += Qgp[(((size_t)g)*12 + h)*4096 + e];
#pragma unroll
    for (int g = 0; g < GK_; ++g) k += Kgp[(((size_t)g)*12 + h)*4096 + e];
    qg[e] = q; kg[e] = k;
  }
  __syncthreads();
  float s2 = 0.f;
#pragma unroll
  for (int i = 0; i < 16; ++i) { int e = i*256 + tid; s2 += qg[e]*kg[e]; }
  float s1 = (tid < 64) ? qsum[h*64 + tid] * ksum[h*64 + tid] : 0.f;
#pragma unroll
  for (int s = 32; s; s >>= 1) { s2 += __shfl_xor(s2, s); s1 += __shfl_xor(s1, s); }
  if (lane == 0) { red[wid] = s2; red[4 + wid] = s1; }
  __syncthreads();
  if (tid == 0) {
    double S2 = (double)red[0] + red[1] + red[2] + red[3];
    double S1 = (double)red[4];          // only wave 0 had s1 contributions
    double M = 8388608.0;                // B*N*N
    double Sb = acc[h], Sb2 = acc[12 + h], Cross = acc[24 + h];
    double Eraw  = (S1 + 8.0 * Sb) / M;
    double Eraw2 = (S2 + 2.0 * Cross + 8.0 * Sb2) / M;
    double var = (double)SCALE_ * (double)SCALE_ * (Eraw2 - Eraw * Eraw);
    double rstd = 1.0 / sqrt(var + 1e-5);
    temp[h] = (float)((double)gamma[h] * (double)SCALE_ * rstd);
  }
}

// ---------------------------------------------------------------- K6: fused flash attention (64 q-rows, 64-key tiles)
__global__ __launch_bounds__(256) void attn_kernel(
    const u16* __restrict__ q, const u16* __restrict__ k, const u16* __restrict__ vT,
    const float* __restrict__ bias, const float* __restrict__ temp, u16* __restrict__ out)
{
  extern __shared__ char smem[];
  u16*  qt = (u16*)smem;              // [2][64][32] bf16, split-k halves
  u16*  kt = qt + 4096;               // [2][64][32]
  u16*  vt = kt + 4096;               // [2 m-half][64 d][32 m]
  float* bl = (float*)(vt + 4096);    // [64 n][64 m] fp32
  u16*  pt = (u16*)(bl + 4096);       // [64][72] bf16 (+8 pad for banks)
  const int tid = threadIdx.x, lane = tid & 63, wid = tid >> 6;
  const int lr = lane & 15, lq = lane >> 4;
  const int n0 = blockIdx.x * 64, h = blockIdx.y, b = blockIdx.z;
  const size_t qbase = ((((size_t)b) * 12 + h) << 16) + ((size_t)n0 << 6);
  const size_t kbase = ((size_t)h) << 16;
  const size_t vbase = ((((size_t)b) * 12 + h) << 16);
  const size_t bbase = (((size_t)h) << 20) + ((size_t)n0 << 10);
  const float tmp = temp[h];

#pragma unroll
  for (int it = 0; it < 2; ++it) {    // q tile once
    int c = it*256 + tid; int ks = c >> 8, r = (c >> 2) & 63, c8 = c & 3;
    gl2lds16(q + qbase + (size_t)r * 64 + ks*32 + c8*8, (char*)qt + (it*256 + wid*64) * 16);
  }
  float mrun[4], lrun[4];
  f32x4 oacc[4] = {};
#pragma unroll
  for (int r = 0; r < 4; ++r) { mrun[r] = -3.0e38f; lrun[r] = 0.f; }

  for (int m0 = 0; m0 < 1024; m0 += 64) {
#pragma unroll
    for (int it = 0; it < 2; ++it) {
      int c = it*256 + tid; int ks = c >> 8, r = (c >> 2) & 63, c8 = c & 3;
      gl2lds16(k  + kbase + (size_t)(m0 + r) * 64 + ks*32 + c8*8, (char*)kt + (it*256 + wid*64) * 16);
      gl2lds16(vT + vbase + (size_t)r * 1024 + m0 + ks*32 + c8*8, (char*)vt + (it*256 + wid*64) * 16);
    }
#pragma unroll
    for (int it = 0; it < 4; ++it) {
      int c = it*256 + tid; int r = c >> 4, c4 = c & 15;
      gl2lds16(bias + bbase + (size_t)r * 1024 + m0 + c4*4, (char*)bl + (it*256 + wid*64) * 16);
    }
    __syncthreads();
    f32x4 s[4] = {};
#pragma unroll
    for (int ks = 0; ks < 2; ++ks) {
      bf16x8 aq = *(const bf16x8*)&qt[ks*2048 + (wid*16 + lr)*32 + lq*8];
#pragma unroll
      for (int nj = 0; nj < 4; ++nj) {
        bf16x8 bk = *(const bf16x8*)&kt[ks*2048 + (nj*16 + lr)*32 + lq*8];
        s[nj] = __builtin_amdgcn_mfma_f32_16x16x32_bf16(aq, bk, s[nj], 0, 0, 0);
      }
    }
    int rowl = wid*16 + lq*4;
#pragma unroll
    for (int r = 0; r < 4; ++r) {
      float lg[4];
#pragma unroll
      for (int nj = 0; nj < 4; ++nj)
        lg[nj] = (s[nj][r] + bl[(rowl + r)*64 + nj*16 + lr]) * tmp;
      float mx = fmaxf(fmaxf(lg[0], lg[1]), fmaxf(lg[2], lg[3]));
#pragma unroll
      for (int sh = 1; sh < 16; sh <<= 1) mx = fmaxf(mx, __shfl_xor(mx, sh));
      float mnew = fmaxf(mrun[r], mx);
      float alpha = __expf(mrun[r] - mnew);
      float ps = 0.f;
#pragma unroll
      for (int nj = 0; nj < 4; ++nj) {
        float p = __expf(lg[nj] - mnew);
        ps += p;
        pt[(rowl + r)*72 + nj*16 + lr] = f2b(p);
      }
#pragma unroll
      for (int sh = 1; sh < 16; sh <<= 1) ps += __shfl_xor(ps, sh);
      lrun[r] = lrun[r] * alpha + ps;
      mrun[r] = mnew;
#pragma unroll
      for (int dj = 0; dj < 4; ++dj) oacc[dj][r] *= alpha;
    }
#pragma unroll
    for (int ks = 0; ks < 2; ++ks) {
      bf16x8 ap = *(const bf16x8*)&pt[(wid*16 + lr)*72 + ks*32 + lq*8];
#pragma unroll
      for (int dj = 0; dj < 4; ++dj) {
        bf16x8 bv = *(const bf16x8*)&vt[ks*2048 + (dj*16 + lr)*32 + lq*8];
        oacc[dj] = __builtin_amdgcn_mfma_f32_16x16x32_bf16(ap, bv, oacc[dj], 0, 0, 0);
      }
    }
    __syncthreads();
  }
#pragma unroll
  for (int dj = 0; dj < 4; ++dj)
#pragma unroll
    for (int r = 0; r < 4; ++r) {
      int n = n0 + wid*16 + lq*4 + r;
      int col = h*64 + dj*16 + lr;
      out[((size_t)(b*1024 + n)) * 768 + col] = f2b(oacc[dj][r] / lrun[r]);
    }
}

// ---------------------------------------------------------------- K7: out = attn @ w_proj^T + b_proj (fp32 out)
__global__ __launch_bounds__(256) void proj_gemm(
    const u16* __restrict__ A, const u16* __restrict__ W,
    const float* __restrict__ bp, float* __restrict__ out)
{
  __shared__ u16 As[128*32];
  __shared__ u16 Bs[128*32];
  const int tid = threadIdx.x, lane = tid & 63, wid = tid >> 6;
  const int m0 = blockIdx.y * 128, n0 = blockIdx.x * 128;
  const int wm = (wid >> 1) * 64, wn = (wid & 1) * 64;
  const int lr = lane & 15, lq = lane >> 4;
  f32x4 acc[4][4] = {};
  for (int k0 = 0; k0 < 768; k0 += 32) {
#pragma unroll
    for (int it = 0; it < 2; ++it) {
      int c = it*256 + tid; int row = c >> 2, c8 = c & 3;
      gl2lds16(A + (size_t)(m0 + row) * 768 + k0 + c8*8, (char*)As + (it*256 + wid*64) * 16);
      gl2lds16(W + (size_t)(n0 + row) * 768 + k0 + c8*8, (char*)Bs + (it*256 + wid*64) * 16);
    }
    __syncthreads();
    bf16x8 af[4], bfr[4];
#pragma unroll
    for (int i = 0; i < 4; ++i) {
      af[i]  = *(const bf16x8*)&As[(wm + i*16 + lr)*32 + lq*8];
      bfr[i] = *(const bf16x8*)&Bs[(wn + i*16 + lr)*32 + lq*8];
    }
#pragma unroll
    for (int mi = 0; mi < 4; ++mi)
#pragma unroll
      for (int nj = 0; nj < 4; ++nj)
        acc[mi][nj] = __builtin_amdgcn_mfma_f32_16x16x32_bf16(af[mi], bfr[nj], acc[mi][nj], 0, 0, 0);
    __syncthreads();
  }
#pragma unroll
  for (int mi = 0; mi < 4; ++mi)
#pragma unroll
    for (int nj = 0; nj < 4; ++nj)
#pragma unroll
      for (int r = 0; r < 4; ++r) {
        int row = m0 + wm + mi*16 + lq*4 + r;
        int col = n0 + wn + nj*16 + lr;
        out[(size_t)row * 768 + col] = acc[mi][nj][r] + bp[col];
      }
}

// ----------------------------------------------------------------
extern "C" void kernel_launch(void* const* d_in, const int* in_sizes, int n_in,
                              void* d_out, int out_size, void* d_ws, size_t ws_size,
                              hipStream_t stream)
{
  const float* x     = (const float*)d_in[0];
  const float* wqv   = (const float*)d_in[1];
  const float* ek    = (const float*)d_in[2];
  const float* ebias = (const float*)d_in[3];
  const float* gamma = (const float*)d_in[4];
  // d_in[5] = bn_beta: cancels inside softmax (per-row constant) — unused.
  const float* wp    = (const float*)d_in[6];
  const float* bp    = (const float*)d_in[7];
  float* out = (float*)d_out;

  char* ws = (char*)d_ws;
  size_t off = 0;
  auto alloc = [&](size_t bytes) { char* p = ws + off; off += (bytes + 255) & ~(size_t)255; return p; };
  u16* x16   = (u16*)alloc((size_t)8192*768*2);   // also reused: gram partials, attn output
  u16* wqv16 = (u16*)alloc((size_t)1536*768*2);
  u16* wp16  = (u16*)alloc((size_t)768*768*2);
  u16* k16   = (u16*)alloc((size_t)12*1024*64*2);
  u16* q16   = (u16*)alloc((size_t)8*12*1024*64*2);
  u16* v16   = (u16*)alloc((size_t)8*12*1024*64*2);
  u16* vt16  = (u16*)alloc((size_t)8*12*1024*64*2);
  float* qs  = (float*)alloc((size_t)12*1024*64*4);
  float* acc = (float*)alloc(3*12*4);
  float* qsum = (float*)alloc(12*64*4);
  float* ksum = (float*)alloc(12*64*4);
  float* temp = (float*)alloc(12*4);
  // Gram partials overlaid on x16 (x16 is dead after qv_gemm; partials are
  // dead after finalize_kernel, which runs before attn writes attn16=x16).
  float* Qgp = (float*)x16;                              // 32*12*4096 f32 = 6.29 MB
  float* Kgp = Qgp + (size_t)GQ_*12*4096;                //  4*12*4096 f32 = 0.79 MB
  u16* attn16 = x16;  // attn output reuses x16 after finalize

  hipMemsetAsync(acc, 0, 3*12*4, stream);

  { // K0: casts (x, w_qv, w_proj, ext_k)
    int c0 = 8192*768/4, c1 = 1536*768/4, c2 = 768*768/4, c3 = 12*1024*64/4;
    int total = c0 + c1 + c2 + c3;
    cast_all<<<(total + 255)/256, 256, 0, stream>>>(
        (const float4*)x, x16, c0, (const float4*)wqv, wqv16, c1,
        (const float4*)wp, wp16, c2, (const float4*)ek, k16, c3);
  }
  qv_gemm<<<dim3(12, 64), 256, 0, stream>>>(x16, wqv16, q16, v16);
  transpose_v<<<dim3(16, 96), 256, 0, stream>>>(v16, vt16);
  qs_kernel<<<3072, 256, 0, stream>>>(q16, qs);
  gram_kernel<<<dim3(GK_, 12), 256, 0, stream>>>(k16, Kgp, 1024/GK_, 0);
  gram_kernel<<<dim3(GQ_, 12), 256, 0, stream>>>(q16, Qgp, 8192/GQ_, 1);
  bias_stats<<<dim3(32, 12), 256, 0, stream>>>(ebias, ek, qs, acc);
  sums_kernel<<<12, 64, 0, stream>>>(qs, k16, qsum, ksum);
  finalize_kernel<<<12, 256, 0, stream>>>(qsum, ksum, Qgp, Kgp, acc, gamma, temp);
  attn_kernel<<<dim3(16, 12, 8), 256, 50176, stream>>>(q16, k16, vt16, ebias, temp, attn16);
  proj_gemm<<<dim3(6, 64), 256, 0, stream>>>(attn16, wp16, bp, out);
}

// Round 3
// 372.969 us; speedup vs baseline: 1.7933x; 1.2420x over previous
//
#include <hip/hip_runtime.h>
#include <cstdint>

// Problem constants
#define B_    8
#define N_    1024
#define DIM_  768
#define H_    12
#define D_    64
#define SCALE_ 0.125f
#define GQ_   32   // partial-gram blocks per head for Q (8192 rows / 256)
#define GK_   4    // partial-gram blocks per head for K (1024 rows / 256)

typedef unsigned short u16;
typedef short bf16x8 __attribute__((ext_vector_type(8)));
typedef float f32x4  __attribute__((ext_vector_type(4)));

__device__ __forceinline__ u16 f2b(float f) {
  union { float f; unsigned u; } v; v.f = f;
  unsigned r = v.u + 0x7FFFu + ((v.u >> 16) & 1u);
  return (u16)(r >> 16);
}
__device__ __forceinline__ float b2f(u16 h) {
  union { unsigned u; float f; } v; v.u = ((unsigned)h) << 16; return v.f;
}
// async global->LDS, 16B per lane; LDS base must be wave-uniform (HW adds lane*16)
__device__ __forceinline__ void gl2lds16(const void* g, void* l) {
  __builtin_amdgcn_global_load_lds(
      (const __attribute__((address_space(1))) void*)g,
      (__attribute__((address_space(3))) void*)l, 16, 0, 0);
}

// ---------------------------------------------------------------- K0: fp32 -> bf16 casts
__global__ __launch_bounds__(256) void cast_all(
    const float4* __restrict__ s0, u16* __restrict__ d0, int n0,
    const float4* __restrict__ s1, u16* __restrict__ d1, int n1,
    const float4* __restrict__ s2, u16* __restrict__ d2, int n2,
    const float4* __restrict__ s3, u16* __restrict__ d3, int n3)
{
  int i = blockIdx.x * 256 + threadIdx.x;
  const float4* s; u16* d; int off;
  if (i < n0)               { s = s0; d = d0; off = i; }
  else if (i < n0+n1)       { s = s1; d = d1; off = i - n0; }
  else if (i < n0+n1+n2)    { s = s2; d = d2; off = i - n0 - n1; }
  else if (i < n0+n1+n2+n3) { s = s3; d = d3; off = i - n0 - n1 - n2; }
  else return;
  float4 v = s[off];
  ushort4 o; o.x = f2b(v.x); o.y = f2b(v.y); o.z = f2b(v.z); o.w = f2b(v.w);
  *(ushort4*)(d + (size_t)off * 4) = o;
}

// ---------------------------------------------------------------- K1: qv = x @ w_qv^T  (bf16 MFMA, m97 pattern)
__global__ __launch_bounds__(256) void qv_gemm(
    const u16* __restrict__ A, const u16* __restrict__ W,
    u16* __restrict__ qo, u16* __restrict__ vo)
{
  __shared__ u16 As[128*32];
  __shared__ u16 Bs[128*32];
  const int tid = threadIdx.x, lane = tid & 63, wid = tid >> 6;
  const int m0 = blockIdx.y * 128, n0 = blockIdx.x * 128;
  const int wm = (wid >> 1) * 64, wn = (wid & 1) * 64;
  const int lr = lane & 15, lq = lane >> 4;
  f32x4 acc[4][4] = {};
  for (int k0 = 0; k0 < 768; k0 += 32) {
#pragma unroll
    for (int it = 0; it < 2; ++it) {
      int c = it * 256 + tid;
      int row = c >> 2, c8 = c & 3;
      gl2lds16(A + (size_t)(m0 + row) * 768 + k0 + c8 * 8, (char*)As + (it*256 + wid*64) * 16);
      gl2lds16(W + (size_t)(n0 + row) * 768 + k0 + c8 * 8, (char*)Bs + (it*256 + wid*64) * 16);
    }
    __syncthreads();
    bf16x8 af[4], bfr[4];
#pragma unroll
    for (int i = 0; i < 4; ++i) {
      af[i]  = *(const bf16x8*)&As[(wm + i*16 + lr) * 32 + lq * 8];
      bfr[i] = *(const bf16x8*)&Bs[(wn + i*16 + lr) * 32 + lq * 8];
    }
#pragma unroll
    for (int mi = 0; mi < 4; ++mi)
#pragma unroll
      for (int nj = 0; nj < 4; ++nj)
        acc[mi][nj] = __builtin_amdgcn_mfma_f32_16x16x32_bf16(af[mi], bfr[nj], acc[mi][nj], 0, 0, 0);
    __syncthreads();
  }
#pragma unroll
  for (int mi = 0; mi < 4; ++mi)
#pragma unroll
    for (int nj = 0; nj < 4; ++nj)
#pragma unroll
      for (int r = 0; r < 4; ++r) {
        int row = m0 + wm + mi*16 + lq*4 + r;   // flat b*N+n
        int col = n0 + wn + nj*16 + lr;         // e in [0,1536)
        u16 bv = f2b(acc[mi][nj][r]);
        int b = row >> 10, n = row & 1023;
        if (col < 768) { int h = col >> 6, d = col & 63;
          qo[(((size_t)(b*12 + h)) << 16) + (n << 6) + d] = bv;
        } else { int e = col - 768; int h = e >> 6, d = e & 63;
          vo[(((size_t)(b*12 + h)) << 16) + (n << 6) + d] = bv;
        }
      }
}

// ---------------------------------------------------------------- K1b: v [BH][1024][64] -> vT [BH][64][1024]
__global__ __launch_bounds__(256) void transpose_v(const u16* __restrict__ v, u16* __restrict__ vt)
{
  __shared__ u16 t[64][65];
  int bh = blockIdx.y, n0 = blockIdx.x * 64, tid = threadIdx.x;
  const u16* src = v + (((size_t)bh) << 16) + (size_t)n0 * 64;
  u16* dst = vt + (((size_t)bh) << 16) + n0;
#pragma unroll
  for (int i = 0; i < 16; ++i) {
    int e = i*256 + tid; t[e >> 6][e & 63] = src[e];
  }
  __syncthreads();
#pragma unroll
  for (int i = 0; i < 16; ++i) {
    int e = i*256 + tid; int d = e >> 6, r = e & 63;
    dst[(size_t)d * 1024 + r] = t[r][d];
  }
}

// ---------------------------------------------------------------- K3: qs[h,n,d] = sum_b q
__global__ __launch_bounds__(256) void qs_kernel(const u16* __restrict__ q, float* __restrict__ qs)
{
  int idx = blockIdx.x * 256 + threadIdx.x;   // 12*1024*64
  int h = idx >> 16, rem = idx & 65535;
  float s = 0.f;
#pragma unroll
  for (int b = 0; b < 8; ++b) s += b2f(q[(((size_t)(b*12 + h)) << 16) + rem]);
  qs[idx] = s;
}

// ---------------------------------------------------------------- K2/K4: 64x64 Gram partials (NO atomics)
__global__ __launch_bounds__(256) void gram_kernel(
    const u16* __restrict__ src, float* __restrict__ gpart,
    int rows_per_block, int b_interleaved)
{
  __shared__ float t[64*68];
  const int h = blockIdx.y, r0 = blockIdx.x * rows_per_block, tid = threadIdx.x;
  const int rr = (tid >> 4) * 4;   // row base 0..60
  const int cc = (tid & 15) * 4;   // col base 0..60
  float a[4][4] = {{0.f}};
  for (int t0 = 0; t0 < rows_per_block; t0 += 64) {
#pragma unroll
    for (int i = 0; i < 4; ++i) {
      int e = i*256 + tid;               // 0..1023 -> 64 rows x 16 ushort4
      int r = e >> 4, d4 = (e & 15) * 4;
      int gr = r0 + t0 + r;
      size_t addr;
      if (b_interleaved) { int b = gr >> 10, n = gr & 1023;
        addr = (((size_t)(b*12 + h)) << 16) + (n << 6) + d4; }
      else addr = (((size_t)h) << 16) + ((size_t)gr << 6) + d4;
      ushort4 u = *(const ushort4*)(src + addr);
      float4 f; f.x = b2f(u.x); f.y = b2f(u.y); f.z = b2f(u.z); f.w = b2f(u.w);
      *(float4*)&t[r*68 + d4] = f;
    }
    __syncthreads();
#pragma unroll 4
    for (int m = 0; m < 64; ++m) {
      float4 rv = *(const float4*)&t[m*68 + rr];
      float4 cv = *(const float4*)&t[m*68 + cc];
      a[0][0] += rv.x*cv.x; a[0][1] += rv.x*cv.y; a[0][2] += rv.x*cv.z; a[0][3] += rv.x*cv.w;
      a[1][0] += rv.y*cv.x; a[1][1] += rv.y*cv.y; a[1][2] += rv.y*cv.z; a[1][3] += rv.y*cv.w;
      a[2][0] += rv.z*cv.x; a[2][1] += rv.z*cv.y; a[2][2] += rv.z*cv.z; a[2][3] += rv.z*cv.w;
      a[3][0] += rv.w*cv.x; a[3][1] += rv.w*cv.y; a[3][2] += rv.w*cv.z; a[3][3] += rv.w*cv.w;
    }
    __syncthreads();
  }
  float* g = gpart + (((size_t)blockIdx.x) * 12 + h) * 4096;
#pragma unroll
  for (int i = 0; i < 4; ++i)
    *(float4*)&g[(rr + i)*64 + cc] = make_float4(a[i][0], a[i][1], a[i][2], a[i][3]);
}

// ---------------------------------------------------------------- K2b: bias sums + cross term (one 50MB pass)
__global__ __launch_bounds__(256) void bias_stats(
    const float* __restrict__ bias, const float* __restrict__ k,
    const float* __restrict__ qs, float* __restrict__ acc)
{
  __shared__ float kt[64*68];
  __shared__ float bt[32*64];
  __shared__ float red[12];
  int h = blockIdx.y, n0 = blockIdx.x * 32;
  int tid = threadIdx.x, lane = tid & 63, wid = tid >> 6;
  int d = tid & 63, rg = tid >> 6;
  float kb[8];
#pragma unroll
  for (int j = 0; j < 8; ++j) kb[j] = 0.f;
  float sb = 0.f, sb2 = 0.f;
  for (int m0 = 0; m0 < 1024; m0 += 64) {
    __syncthreads();
#pragma unroll
    for (int i = 0; i < 4; ++i) {            // k tile 64x64 fp32
      int f = i*256 + tid; int r = f >> 4, c4 = (f & 15) * 4;
      float4 kv = *(const float4*)(k + (((size_t)h) << 16) + (size_t)(m0 + r) * 64 + c4);
      *(float4*)&kt[r*68 + c4] = kv;
    }
#pragma unroll
    for (int i = 0; i < 2; ++i) {            // bias tile 32x64 fp32
      int f = i*256 + tid; int r = f >> 4, c4 = (f & 15) * 4;
      float4 bv = *(const float4*)(bias + (((size_t)h) << 20) + (size_t)(n0 + r) * 1024 + m0 + c4);
      *(float4*)&bt[r*64 + c4] = bv;
      sb  += bv.x + bv.y + bv.z + bv.w;
      sb2 += bv.x*bv.x + bv.y*bv.y + bv.z*bv.z + bv.w*bv.w;
    }
    __syncthreads();
    for (int m = 0; m < 64; ++m) {
      float kv = kt[m*68 + d];
#pragma unroll
      for (int j = 0; j < 8; ++j) kb[j] += bt[(rg + 4*j)*64 + m] * kv;
    }
  }
  float cross = 0.f;
#pragma unroll
  for (int j = 0; j < 8; ++j)
    cross += kb[j] * qs[(((size_t)h) << 16) + (size_t)(n0 + rg + 4*j) * 64 + d];
#pragma unroll
  for (int s = 32; s; s >>= 1) {
    sb += __shfl_xor(sb, s); sb2 += __shfl_xor(sb2, s); cross += __shfl_xor(cross, s);
  }
  if (lane == 0) { red[wid] = sb; red[4 + wid] = sb2; red[8 + wid] = cross; }
  __syncthreads();
  if (tid == 0) {
    atomicAdd(acc + h,      red[0] + red[1] + red[2] + red[3]);
    atomicAdd(acc + 12 + h, red[4] + red[5] + red[6] + red[7]);
    atomicAdd(acc + 24 + h, red[8] + red[9] + red[10] + red[11]);
  }
}

// ---------------------------------------------------------------- K4b: qsum/ksum per head (parallel partials)
// grid (12, 9): y<8 -> qsum partial over 128 n-rows (atomicAdd, zero-inited);
//               y==8 -> ksum full (plain store).
__global__ __launch_bounds__(256) void sums_kernel(
    const float* __restrict__ qs, const u16* __restrict__ kb16,
    float* __restrict__ qsum, float* __restrict__ ksum)
{
  __shared__ float red[256];
  int h = blockIdx.x, yc = blockIdx.y;
  int tid = threadIdx.x, d = tid & 63, qq = tid >> 6;
  if (yc < 8) {
    float s = 0.f;
    int nbase = yc * 128 + qq * 32;
    for (int n = 0; n < 32; ++n)
      s += qs[(((size_t)h) << 16) + ((size_t)(nbase + n) << 6) + d];
    red[tid] = s; __syncthreads();
    if (qq == 0) atomicAdd(&qsum[h*64 + d], red[d] + red[64+d] + red[128+d] + red[192+d]);
  } else {
    float s = 0.f;
    int nbase = qq * 256;
    for (int n = 0; n < 256; ++n)
      s += b2f(kb16[(((size_t)h) << 16) + ((size_t)(nbase + n) << 6) + d]);
    red[tid] = s; __syncthreads();
    if (qq == 0) ksum[h*64 + d] = red[d] + red[64+d] + red[128+d] + red[192+d];
  }
}

// ---------------------------------------------------------------- K5: reduce gram partials + assemble var -> temp[h]
__global__ __launch_bounds__(256) void finalize_kernel(
    const float* __restrict__ qsum, const float* __restrict__ ksum,
    const float* __restrict__ Qgp, const float* __restrict__ Kgp,
    const float* __restrict__ acc, const float* __restrict__ gamma,
    float* __restrict__ temp)
{
  __shared__ float qg[4096];
  __shared__ float kg[4096];
  __shared__ float red[8];
  int h = blockIdx.x, tid = threadIdx.x, wid = tid >> 6, lane = tid & 63;
#pragma unroll
  for (int i = 0; i < 16; ++i) {
    int e = i*256 + tid;
    float q = 0.f, k = 0.f;
    for (int g = 0; g < GQ_; ++g) q += Qgp[(((size_t)g)*12 + h)*4096 + e];
#pragma unroll
    for (int g = 0; g < GK_; ++g) k += Kgp[(((size_t)g)*12 + h)*4096 + e];
    qg[e] = q; kg[e] = k;
  }
  __syncthreads();
  float s2 = 0.f;
#pragma unroll
  for (int i = 0; i < 16; ++i) { int e = i*256 + tid; s2 += qg[e]*kg[e]; }
  float s1 = (tid < 64) ? qsum[h*64 + tid] * ksum[h*64 + tid] : 0.f;
#pragma unroll
  for (int s = 32; s; s >>= 1) { s2 += __shfl_xor(s2, s); s1 += __shfl_xor(s1, s); }
  if (lane == 0) { red[wid] = s2; red[4 + wid] = s1; }
  __syncthreads();
  if (tid == 0) {
    double S2 = (double)red[0] + red[1] + red[2] + red[3];
    double S1 = (double)red[4];          // only wave 0 had s1 contributions
    double M = 8388608.0;                // B*N*N
    double Sb = acc[h], Sb2 = acc[12 + h], Cross = acc[24 + h];
    double Eraw  = (S1 + 8.0 * Sb) / M;
    double Eraw2 = (S2 + 2.0 * Cross + 8.0 * Sb2) / M;
    double var = (double)SCALE_ * (double)SCALE_ * (Eraw2 - Eraw * Eraw);
    double rstd = 1.0 / sqrt(var + 1e-5);
    temp[h] = (float)((double)gamma[h] * (double)SCALE_ * rstd);
  }
}

// ---------------------------------------------------------------- K6: fused flash attention v2
// BN-normalized logits => |logit| small => NO max tracking needed: accumulate
// unnormalized exp, get row-sum l via ones-column MFMA (V^T row 64 = 1).
// Bias read global->VGPR (no LDS tile, no bank conflicts). XCD swizzle: the
// 8 b-blocks sharing one (n0,h) bias tile land on the same XCD consecutively.
__global__ __launch_bounds__(256) void attn_kernel(
    const u16* __restrict__ q, const u16* __restrict__ k, const u16* __restrict__ vT,
    const float* __restrict__ bias, const float* __restrict__ temp, u16* __restrict__ out)
{
  __shared__ u16 qt[4096];       // [2 ks][64 n][32 k]
  __shared__ u16 kt[4096];       // [2 ks][64 m][32 k]
  __shared__ u16 vt[5120];       // [2 ks][80 d][32 m]  (rows 64..79: ones-column pad)
  __shared__ u16 pt[64*72];      // P round-trip, +8 pad
  const int tid = threadIdx.x, lane = tid & 63, wid = tid >> 6;
  const int lr = lane & 15, lq = lane >> 4;
  // swizzled decode: X = g*64 + b*8 + q8, pair p = g*8 + q8 -> same-XCD b-groups
  const int X = blockIdx.x;
  const int g = X >> 6, r_ = X & 63, b = r_ >> 3, q8 = r_ & 7;
  const int p = g*8 + q8;
  const int h = p % 12, n0 = (p / 12) * 64;
  const size_t qbase = ((((size_t)b) * 12 + h) << 16) + ((size_t)n0 << 6);
  const size_t kbase = ((size_t)h) << 16;
  const size_t vbase = ((((size_t)b) * 12 + h) << 16);
  const size_t bbase = (((size_t)h) << 20) + ((size_t)n0 << 10);
  const float tmp = temp[h];
  const int rowl = wid*16 + lq*4;

#pragma unroll
  for (int it = 0; it < 2; ++it) {    // q tile once
    int c = it*256 + tid; int ks = c >> 8, r = (c >> 2) & 63, c8 = c & 3;
    gl2lds16(q + qbase + (size_t)r * 64 + ks*32 + c8*8, (char*)qt + (it*256 + wid*64) * 16);
  }
  for (int i = tid; i < 1024; i += 256) {  // ones-column rows (persist across tiles)
    int ks = i >> 9, rr = (i >> 5) & 15, cc = i & 31;
    vt[ks*2560 + (64 + rr)*32 + cc] = (rr == 0) ? (u16)0x3F80 : (u16)0;
  }
  f32x4 oacc[5] = {};   // [0..3]=O cols, [4]=l (ones column)

  for (int m0 = 0; m0 < 1024; m0 += 64) {
#pragma unroll
    for (int it = 0; it < 2; ++it) {
      int c = it*256 + tid; int ks = c >> 8, r = (c >> 2) & 63, c8 = c & 3;
      gl2lds16(k  + kbase + (size_t)(m0 + r) * 64 + ks*32 + c8*8, (char*)kt + (it*256 + wid*64) * 16);
      gl2lds16(vT + vbase + (size_t)r * 1024 + m0 + ks*32 + c8*8, (char*)vt + it*5120 + wid*1024);
    }
    // bias -> registers (global, mostly L2-hit after swizzle)
    float breg[4][4];
#pragma unroll
    for (int r = 0; r < 4; ++r)
#pragma unroll
      for (int nj = 0; nj < 4; ++nj)
        breg[r][nj] = bias[bbase + (size_t)(rowl + r) * 1024 + m0 + nj*16 + lr];
    __syncthreads();
    // S = q @ k^T
    f32x4 s[4] = {};
#pragma unroll
    for (int ks = 0; ks < 2; ++ks) {
      bf16x8 aq = *(const bf16x8*)&qt[ks*2048 + (wid*16 + lr)*32 + lq*8];
#pragma unroll
      for (int nj = 0; nj < 4; ++nj) {
        bf16x8 bk = *(const bf16x8*)&kt[ks*2048 + (nj*16 + lr)*32 + lq*8];
        s[nj] = __builtin_amdgcn_mfma_f32_16x16x32_bf16(aq, bk, s[nj], 0, 0, 0);
      }
    }
    // unnormalized exp (no max, no rescale: BN bounds the logits)
#pragma unroll
    for (int r = 0; r < 4; ++r)
#pragma unroll
      for (int nj = 0; nj < 4; ++nj) {
        float pv = __expf((s[nj][r] + breg[r][nj]) * tmp);
        pt[(rowl + r)*72 + nj*16 + lr] = f2b(pv);
      }
    // O += P @ [V | 1]
#pragma unroll
    for (int ks = 0; ks < 2; ++ks) {
      bf16x8 ap = *(const bf16x8*)&pt[(wid*16 + lr)*72 + ks*32 + lq*8];
#pragma unroll
      for (int dj = 0; dj < 5; ++dj) {
        bf16x8 bv = *(const bf16x8*)&vt[ks*2560 + (dj*16 + lr)*32 + lq*8];
        oacc[dj] = __builtin_amdgcn_mfma_f32_16x16x32_bf16(ap, bv, oacc[dj], 0, 0, 0);
      }
    }
    __syncthreads();
  }
  // l for my rows lives in lane lq*16 (col 0 of the ones tile)
#pragma unroll
  for (int r = 0; r < 4; ++r) {
    float l = __shfl(oacc[4][r], lane & 48);
    float linv = 1.f / l;
    int n = n0 + rowl + r;
#pragma unroll
    for (int dj = 0; dj < 4; ++dj) {
      int col = h*64 + dj*16 + lr;
      out[((size_t)(b*1024 + n)) * 768 + col] = f2b(oacc[dj][r] * linv);
    }
  }
}

// ---------------------------------------------------------------- K7: out = attn @ w_proj^T + b_proj (fp32 out)
__global__ __launch_bounds__(256) void proj_gemm(
    const u16* __restrict__ A, const u16* __restrict__ W,
    const float* __restrict__ bp, float* __restrict__ out)
{
  __shared__ u16 As[128*32];
  __shared__ u16 Bs[128*32];
  const int tid = threadIdx.x, lane = tid & 63, wid = tid >> 6;
  const int m0 = blockIdx.y * 128, n0 = blockIdx.x * 128;
  const int wm = (wid >> 1) * 64, wn = (wid & 1) * 64;
  const int lr = lane & 15, lq = lane >> 4;
  f32x4 acc[4][4] = {};
  for (int k0 = 0; k0 < 768; k0 += 32) {
#pragma unroll
    for (int it = 0; it < 2; ++it) {
      int c = it*256 + tid; int row = c >> 2, c8 = c & 3;
      gl2lds16(A + (size_t)(m0 + row) * 768 + k0 + c8*8, (char*)As + (it*256 + wid*64) * 16);
      gl2lds16(W + (size_t)(n0 + row) * 768 + k0 + c8*8, (char*)Bs + (it*256 + wid*64) * 16);
    }
    __syncthreads();
    bf16x8 af[4], bfr[4];
#pragma unroll
    for (int i = 0; i < 4; ++i) {
      af[i]  = *(const bf16x8*)&As[(wm + i*16 + lr)*32 + lq*8];
      bfr[i] = *(const bf16x8*)&Bs[(wn + i*16 + lr)*32 + lq*8];
    }
#pragma unroll
    for (int mi = 0; mi < 4; ++mi)
#pragma unroll
      for (int nj = 0; nj < 4; ++nj)
        acc[mi][nj] = __builtin_amdgcn_mfma_f32_16x16x32_bf16(af[mi], bfr[nj], acc[mi][nj], 0, 0, 0);
    __syncthreads();
  }
#pragma unroll
  for (int mi = 0; mi < 4; ++mi)
#pragma unroll
    for (int nj = 0; nj < 4; ++nj)
#pragma unroll
      for (int r = 0; r < 4; ++r) {
        int row = m0 + wm + mi*16 + lq*4 + r;
        int col = n0 + wn + nj*16 + lr;
        out[(size_t)row * 768 + col] = acc[mi][nj][r] + bp[col];
      }
}

// ----------------------------------------------------------------
extern "C" void kernel_launch(void* const* d_in, const int* in_sizes, int n_in,
                              void* d_out, int out_size, void* d_ws, size_t ws_size,
                              hipStream_t stream)
{
  const float* x     = (const float*)d_in[0];
  const float* wqv   = (const float*)d_in[1];
  const float* ek    = (const float*)d_in[2];
  const float* ebias = (const float*)d_in[3];
  const float* gamma = (const float*)d_in[4];
  // d_in[5] = bn_beta: cancels inside softmax (per-row constant) — unused.
  const float* wp    = (const float*)d_in[6];
  const float* bp    = (const float*)d_in[7];
  float* out = (float*)d_out;

  char* ws = (char*)d_ws;
  size_t off = 0;
  auto alloc = [&](size_t bytes) { char* p = ws + off; off += (bytes + 255) & ~(size_t)255; return p; };
  u16* x16   = (u16*)alloc((size_t)8192*768*2);   // also reused: gram partials, attn output
  u16* wqv16 = (u16*)alloc((size_t)1536*768*2);
  u16* wp16  = (u16*)alloc((size_t)768*768*2);
  u16* k16   = (u16*)alloc((size_t)12*1024*64*2);
  u16* q16   = (u16*)alloc((size_t)8*12*1024*64*2);
  u16* v16   = (u16*)alloc((size_t)8*12*1024*64*2);
  u16* vt16  = (u16*)alloc((size_t)8*12*1024*64*2);
  float* qs  = (float*)alloc((size_t)12*1024*64*4);
  float* acc = (float*)alloc(3*12*4);          // zero region start
  float* qsum = (float*)alloc(12*64*4);
  float* ksum = (float*)alloc(12*64*4);
  size_t zbytes = (size_t)(((char*)ksum + 12*64*4) - (char*)acc);
  float* temp = (float*)alloc(12*4);
  // Gram partials overlaid on x16 (dead after qv_gemm; partials dead after finalize)
  float* Qgp = (float*)x16;                    // 32*12*4096 f32 = 6.29 MB
  float* Kgp = Qgp + (size_t)GQ_*12*4096;      //  4*12*4096 f32 = 0.79 MB
  u16* attn16 = x16;                           // attn output reuses x16 after finalize

  hipMemsetAsync(acc, 0, zbytes, stream);

  { // K0: casts (x, w_qv, w_proj, ext_k)
    int c0 = 8192*768/4, c1 = 1536*768/4, c2 = 768*768/4, c3 = 12*1024*64/4;
    int total = c0 + c1 + c2 + c3;
    cast_all<<<(total + 255)/256, 256, 0, stream>>>(
        (const float4*)x, x16, c0, (const float4*)wqv, wqv16, c1,
        (const float4*)wp, wp16, c2, (const float4*)ek, k16, c3);
  }
  qv_gemm<<<dim3(12, 64), 256, 0, stream>>>(x16, wqv16, q16, v16);
  transpose_v<<<dim3(16, 96), 256, 0, stream>>>(v16, vt16);
  qs_kernel<<<3072, 256, 0, stream>>>(q16, qs);
  gram_kernel<<<dim3(GK_, 12), 256, 0, stream>>>(k16, Kgp, 1024/GK_, 0);
  gram_kernel<<<dim3(GQ_, 12), 256, 0, stream>>>(q16, Qgp, 8192/GQ_, 1);
  bias_stats<<<dim3(32, 12), 256, 0, stream>>>(ebias, ek, qs, acc);
  sums_kernel<<<dim3(12, 9), 256, 0, stream>>>(qs, k16, qsum, ksum);
  finalize_kernel<<<12, 256, 0, stream>>>(qsum, ksum, Qgp, Kgp, acc, gamma, temp);
  attn_kernel<<<dim3(1536), 256, 0, stream>>>(q16, k16, vt16, ebias, temp, attn16);
  proj_gemm<<<dim3(6, 64), 256, 0, stream>>>(attn16, wp16, bp, out);
}

// Round 4
// 323.082 us; speedup vs baseline: 2.0702x; 1.1544x over previous
//
#include <hip/hip_runtime.h>
#include <cstdint>

// Problem constants
#define B_    8
#define N_    1024
#define DIM_  768
#define H_    12
#define D_    64
#define SCALE_ 0.125f
#define GQ_   32   // partial-gram blocks per head for Q (8192 rows / 256)
#define GK_   4    // partial-gram blocks per head for K (1024 rows / 256)

typedef unsigned short u16;
typedef short bf16x8 __attribute__((ext_vector_type(8)));
typedef float f32x4  __attribute__((ext_vector_type(4)));

__device__ __forceinline__ u16 f2b(float f) {
  union { float f; unsigned u; } v; v.f = f;
  unsigned r = v.u + 0x7FFFu + ((v.u >> 16) & 1u);
  return (u16)(r >> 16);
}
__device__ __forceinline__ float b2f(u16 h) {
  union { unsigned u; float f; } v; v.u = ((unsigned)h) << 16; return v.f;
}
// async global->LDS, 16B per lane; LDS base must be wave-uniform (HW adds lane*16)
__device__ __forceinline__ void gl2lds16(const void* g, void* l) {
  __builtin_amdgcn_global_load_lds(
      (const __attribute__((address_space(1))) void*)g,
      (__attribute__((address_space(3))) void*)l, 16, 0, 0);
}

// ---------------------------------------------------------------- K0: fp32 -> bf16 casts
__global__ __launch_bounds__(256) void cast_all(
    const float4* __restrict__ s0, u16* __restrict__ d0, int n0,
    const float4* __restrict__ s1, u16* __restrict__ d1, int n1,
    const float4* __restrict__ s2, u16* __restrict__ d2, int n2,
    const float4* __restrict__ s3, u16* __restrict__ d3, int n3)
{
  int i = blockIdx.x * 256 + threadIdx.x;
  const float4* s; u16* d; int off;
  if (i < n0)               { s = s0; d = d0; off = i; }
  else if (i < n0+n1)       { s = s1; d = d1; off = i - n0; }
  else if (i < n0+n1+n2)    { s = s2; d = d2; off = i - n0 - n1; }
  else if (i < n0+n1+n2+n3) { s = s3; d = d3; off = i - n0 - n1 - n2; }
  else return;
  float4 v = s[off];
  ushort4 o; o.x = f2b(v.x); o.y = f2b(v.y); o.z = f2b(v.z); o.w = f2b(v.w);
  *(ushort4*)(d + (size_t)off * 4) = o;
}

// ---------------------------------------------------------------- K1: qv = x @ w_qv^T  (bf16 MFMA, m97 pattern)
__global__ __launch_bounds__(256) void qv_gemm(
    const u16* __restrict__ A, const u16* __restrict__ W,
    u16* __restrict__ qo, u16* __restrict__ vo)
{
  __shared__ u16 As[128*32];
  __shared__ u16 Bs[128*32];
  const int tid = threadIdx.x, lane = tid & 63, wid = tid >> 6;
  const int m0 = blockIdx.y * 128, n0 = blockIdx.x * 128;
  const int wm = (wid >> 1) * 64, wn = (wid & 1) * 64;
  const int lr = lane & 15, lq = lane >> 4;
  f32x4 acc[4][4] = {};
  for (int k0 = 0; k0 < 768; k0 += 32) {
#pragma unroll
    for (int it = 0; it < 2; ++it) {
      int c = it * 256 + tid;
      int row = c >> 2, c8 = c & 3;
      gl2lds16(A + (size_t)(m0 + row) * 768 + k0 + c8 * 8, (char*)As + (it*256 + wid*64) * 16);
      gl2lds16(W + (size_t)(n0 + row) * 768 + k0 + c8 * 8, (char*)Bs + (it*256 + wid*64) * 16);
    }
    __syncthreads();
    bf16x8 af[4], bfr[4];
#pragma unroll
    for (int i = 0; i < 4; ++i) {
      af[i]  = *(const bf16x8*)&As[(wm + i*16 + lr) * 32 + lq * 8];
      bfr[i] = *(const bf16x8*)&Bs[(wn + i*16 + lr) * 32 + lq * 8];
    }
#pragma unroll
    for (int mi = 0; mi < 4; ++mi)
#pragma unroll
      for (int nj = 0; nj < 4; ++nj)
        acc[mi][nj] = __builtin_amdgcn_mfma_f32_16x16x32_bf16(af[mi], bfr[nj], acc[mi][nj], 0, 0, 0);
    __syncthreads();
  }
#pragma unroll
  for (int mi = 0; mi < 4; ++mi)
#pragma unroll
    for (int nj = 0; nj < 4; ++nj)
#pragma unroll
      for (int r = 0; r < 4; ++r) {
        int row = m0 + wm + mi*16 + lq*4 + r;   // flat b*N+n
        int col = n0 + wn + nj*16 + lr;         // e in [0,1536)
        u16 bv = f2b(acc[mi][nj][r]);
        int b = row >> 10, n = row & 1023;
        if (col < 768) { int h = col >> 6, d = col & 63;
          qo[(((size_t)(b*12 + h)) << 16) + (n << 6) + d] = bv;
        } else { int e = col - 768; int h = e >> 6, d = e & 63;
          vo[(((size_t)(b*12 + h)) << 16) + (n << 6) + d] = bv;
        }
      }
}

// ---------------------------------------------------------------- K1b: transpose v [BH][1024][64]->[BH][64][1024]
// and (y>=96) k [H][1024][64] -> ktT [H][64][1024]
__global__ __launch_bounds__(256) void transpose_v(
    const u16* __restrict__ v, u16* __restrict__ vt,
    const u16* __restrict__ kk, u16* __restrict__ ktT)
{
  __shared__ u16 t[64][65];
  int y = blockIdx.y, n0 = blockIdx.x * 64, tid = threadIdx.x;
  const u16* src; u16* dst;
  if (y < 96) { src = v  + (((size_t)y) << 16) + (size_t)n0 * 64;      dst = vt  + (((size_t)y) << 16) + n0; }
  else { int h = y - 96; src = kk + (((size_t)h) << 16) + (size_t)n0 * 64; dst = ktT + (((size_t)h) << 16) + n0; }
#pragma unroll
  for (int i = 0; i < 16; ++i) {
    int e = i*256 + tid; t[e >> 6][e & 63] = src[e];
  }
  __syncthreads();
#pragma unroll
  for (int i = 0; i < 16; ++i) {
    int e = i*256 + tid; int d = e >> 6, r = e & 63;
    dst[(size_t)d * 1024 + r] = t[r][d];
  }
}

// ---------------------------------------------------------------- K3: qs[h,n,d] = sum_b q
__global__ __launch_bounds__(256) void qs_kernel(const u16* __restrict__ q, float* __restrict__ qs)
{
  int idx = blockIdx.x * 256 + threadIdx.x;   // 12*1024*64
  int h = idx >> 16, rem = idx & 65535;
  float s = 0.f;
#pragma unroll
  for (int b = 0; b < 8; ++b) s += b2f(q[(((size_t)(b*12 + h)) << 16) + rem]);
  qs[idx] = s;
}

// ---------------------------------------------------------------- K2/K4: 64x64 Gram partials (NO atomics)
__global__ __launch_bounds__(256) void gram_kernel(
    const u16* __restrict__ src, float* __restrict__ gpart,
    int rows_per_block, int b_interleaved)
{
  __shared__ float t[64*68];
  const int h = blockIdx.y, r0 = blockIdx.x * rows_per_block, tid = threadIdx.x;
  const int rr = (tid >> 4) * 4;   // row base 0..60
  const int cc = (tid & 15) * 4;   // col base 0..60
  float a[4][4] = {{0.f}};
  for (int t0 = 0; t0 < rows_per_block; t0 += 64) {
#pragma unroll
    for (int i = 0; i < 4; ++i) {
      int e = i*256 + tid;               // 0..1023 -> 64 rows x 16 ushort4
      int r = e >> 4, d4 = (e & 15) * 4;
      int gr = r0 + t0 + r;
      size_t addr;
      if (b_interleaved) { int b = gr >> 10, n = gr & 1023;
        addr = (((size_t)(b*12 + h)) << 16) + (n << 6) + d4; }
      else addr = (((size_t)h) << 16) + ((size_t)gr << 6) + d4;
      ushort4 u = *(const ushort4*)(src + addr);
      float4 f; f.x = b2f(u.x); f.y = b2f(u.y); f.z = b2f(u.z); f.w = b2f(u.w);
      *(float4*)&t[r*68 + d4] = f;
    }
    __syncthreads();
#pragma unroll 4
    for (int m = 0; m < 64; ++m) {
      float4 rv = *(const float4*)&t[m*68 + rr];
      float4 cv = *(const float4*)&t[m*68 + cc];
      a[0][0] += rv.x*cv.x; a[0][1] += rv.x*cv.y; a[0][2] += rv.x*cv.z; a[0][3] += rv.x*cv.w;
      a[1][0] += rv.y*cv.x; a[1][1] += rv.y*cv.y; a[1][2] += rv.y*cv.z; a[1][3] += rv.y*cv.w;
      a[2][0] += rv.z*cv.x; a[2][1] += rv.z*cv.y; a[2][2] += rv.z*cv.z; a[2][3] += rv.z*cv.w;
      a[3][0] += rv.w*cv.x; a[3][1] += rv.w*cv.y; a[3][2] += rv.w*cv.z; a[3][3] += rv.w*cv.w;
    }
    __syncthreads();
  }
  float* g = gpart + (((size_t)blockIdx.x) * 12 + h) * 4096;
#pragma unroll
  for (int i = 0; i < 4; ++i)
    *(float4*)&g[(rr + i)*64 + cc] = make_float4(a[i][0], a[i][1], a[i][2], a[i][3]);
}

// ---------------------------------------------------------------- K2b: bias stats v2 — register-only MFMA
// Cross = sum qs[n,d]*bias[n,m]*k[m,d]: bias A-frag straight from global fp32
// (coalesced, also feeds Sb/Sb2), k^T B-frag straight from global bf16 (L2).
// grid (16 nb * 4 mb, 12 h) = 768 blocks; 3 atomics per block.
__global__ __launch_bounds__(256) void bias_stats(
    const float* __restrict__ bias, const u16* __restrict__ ktT,
    const float* __restrict__ qs, float* __restrict__ acc)
{
  __shared__ float red[12];
  const int tid = threadIdx.x, lane = tid & 63, wid = tid >> 6;
  const int lr = lane & 15, lq = lane >> 4;
  const int h = blockIdx.y;
  const int nb = blockIdx.x & 15, mb = blockIdx.x >> 4;
  const int n0 = nb * 64 + wid * 16;          // wave's 16 n-rows
  const size_t brow = (((size_t)h) << 20) + ((size_t)(n0 + lr) << 10);
  const size_t kbase = ((size_t)h) << 16;
  f32x4 kb[4] = {};
  float sb = 0.f, sb2 = 0.f;
#pragma unroll
  for (int ms = 0; ms < 4; ++ms) {
    const int m0 = mb * 256 + ms * 64;
#pragma unroll
    for (int ks = 0; ks < 2; ++ks) {
      const int mc = m0 + ks * 32 + lq * 8;
      float4 b0 = *(const float4*)(bias + brow + mc);
      float4 b1 = *(const float4*)(bias + brow + mc + 4);
      sb  += b0.x + b0.y + b0.z + b0.w + b1.x + b1.y + b1.z + b1.w;
      sb2 += b0.x*b0.x + b0.y*b0.y + b0.z*b0.z + b0.w*b0.w
           + b1.x*b1.x + b1.y*b1.y + b1.z*b1.z + b1.w*b1.w;
      union { bf16x8 v; u16 u[8]; } af;
      af.u[0] = f2b(b0.x); af.u[1] = f2b(b0.y); af.u[2] = f2b(b0.z); af.u[3] = f2b(b0.w);
      af.u[4] = f2b(b1.x); af.u[5] = f2b(b1.y); af.u[6] = f2b(b1.z); af.u[7] = f2b(b1.w);
#pragma unroll
      for (int dj = 0; dj < 4; ++dj) {
        bf16x8 bfr = *(const bf16x8*)(ktT + kbase + (size_t)(dj*16 + lr) * 1024 + mc);
        kb[dj] = __builtin_amdgcn_mfma_f32_16x16x32_bf16(af.v, bfr, kb[dj], 0, 0, 0);
      }
    }
  }
  // cross: kb C-layout row=lq*4+r (n within wave's 16), col=dj*16+lr (d)
  float cross = 0.f;
#pragma unroll
  for (int dj = 0; dj < 4; ++dj)
#pragma unroll
    for (int r = 0; r < 4; ++r)
      cross += kb[dj][r] *
               qs[kbase + ((size_t)(nb*64 + wid*16 + lq*4 + r) << 6) + dj*16 + lr];
#pragma unroll
  for (int s = 32; s; s >>= 1) {
    sb += __shfl_xor(sb, s); sb2 += __shfl_xor(sb2, s); cross += __shfl_xor(cross, s);
  }
  if (lane == 0) { red[wid] = sb; red[4 + wid] = sb2; red[8 + wid] = cross; }
  __syncthreads();
  if (tid == 0) {
    atomicAdd(acc + h,      red[0] + red[1] + red[2] + red[3]);
    atomicAdd(acc + 12 + h, red[4] + red[5] + red[6] + red[7]);
    atomicAdd(acc + 24 + h, red[8] + red[9] + red[10] + red[11]);
  }
}

// ---------------------------------------------------------------- K4b: qsum/ksum per head (parallel partials)
__global__ __launch_bounds__(256) void sums_kernel(
    const float* __restrict__ qs, const u16* __restrict__ kb16,
    float* __restrict__ qsum, float* __restrict__ ksum)
{
  __shared__ float red[256];
  int h = blockIdx.x, yc = blockIdx.y;
  int tid = threadIdx.x, d = tid & 63, qq = tid >> 6;
  if (yc < 8) {
    float s = 0.f;
    int nbase = yc * 128 + qq * 32;
    for (int n = 0; n < 32; ++n)
      s += qs[(((size_t)h) << 16) + ((size_t)(nbase + n) << 6) + d];
    red[tid] = s; __syncthreads();
    if (qq == 0) atomicAdd(&qsum[h*64 + d], red[d] + red[64+d] + red[128+d] + red[192+d]);
  } else {
    float s = 0.f;
    int nbase = qq * 256;
    for (int n = 0; n < 256; ++n)
      s += b2f(kb16[(((size_t)h) << 16) + ((size_t)(nbase + n) << 6) + d]);
    red[tid] = s; __syncthreads();
    if (qq == 0) ksum[h*64 + d] = red[d] + red[64+d] + red[128+d] + red[192+d];
  }
}

// ---------------------------------------------------------------- K5: reduce gram partials + assemble var -> temp[h]
__global__ __launch_bounds__(256) void finalize_kernel(
    const float* __restrict__ qsum, const float* __restrict__ ksum,
    const float* __restrict__ Qgp, const float* __restrict__ Kgp,
    const float* __restrict__ acc, const float* __restrict__ gamma,
    float* __restrict__ temp)
{
  __shared__ float qg[4096];
  __shared__ float kg[4096];
  __shared__ float red[8];
  int h = blockIdx.x, tid = threadIdx.x, wid = tid >> 6, lane = tid & 63;
#pragma unroll
  for (int i = 0; i < 16; ++i) {
    int e = i*256 + tid;
    float q = 0.f, k = 0.f;
    for (int g = 0; g < GQ_; ++g) q += Qgp[(((size_t)g)*12 + h)*4096 + e];
#pragma unroll
    for (int g = 0; g < GK_; ++g) k += Kgp[(((size_t)g)*12 + h)*4096 + e];
    qg[e] = q; kg[e] = k;
  }
  __syncthreads();
  float s2 = 0.f;
#pragma unroll
  for (int i = 0; i < 16; ++i) { int e = i*256 + tid; s2 += qg[e]*kg[e]; }
  float s1 = (tid < 64) ? qsum[h*64 + tid] * ksum[h*64 + tid] : 0.f;
#pragma unroll
  for (int s = 32; s; s >>= 1) { s2 += __shfl_xor(s2, s); s1 += __shfl_xor(s1, s); }
  if (lane == 0) { red[wid] = s2; red[4 + wid] = s1; }
  __syncthreads();
  if (tid == 0) {
    double S2 = (double)red[0] + red[1] + red[2] + red[3];
    double S1 = (double)red[4];          // only wave 0 had s1 contributions
    double M = 8388608.0;                // B*N*N
    double Sb = acc[h], Sb2 = acc[12 + h], Cross = acc[24 + h];
    double Eraw  = (S1 + 8.0 * Sb) / M;
    double Eraw2 = (S2 + 2.0 * Cross + 8.0 * Sb2) / M;
    double var = (double)SCALE_ * (double)SCALE_ * (Eraw2 - Eraw * Eraw);
    double rstd = 1.0 / sqrt(var + 1e-5);
    temp[h] = (float)((double)gamma[h] * (double)SCALE_ * rstd);
  }
}

// ---------------------------------------------------------------- K6: fused flash attention v2
__global__ __launch_bounds__(256) void attn_kernel(
    const u16* __restrict__ q, const u16* __restrict__ k, const u16* __restrict__ vT,
    const float* __restrict__ bias, const float* __restrict__ temp, u16* __restrict__ out)
{
  __shared__ u16 qt[4096];       // [2 ks][64 n][32 k]
  __shared__ u16 kt[4096];       // [2 ks][64 m][32 k]
  __shared__ u16 vt[5120];       // [2 ks][80 d][32 m]  (rows 64..79: ones-column pad)
  __shared__ u16 pt[64*72];      // P round-trip, +8 pad
  const int tid = threadIdx.x, lane = tid & 63, wid = tid >> 6;
  const int lr = lane & 15, lq = lane >> 4;
  const int X = blockIdx.x;
  const int g = X >> 6, r_ = X & 63, b = r_ >> 3, q8 = r_ & 7;
  const int p = g*8 + q8;
  const int h = p % 12, n0 = (p / 12) * 64;
  const size_t qbase = ((((size_t)b) * 12 + h) << 16) + ((size_t)n0 << 6);
  const size_t kbase = ((size_t)h) << 16;
  const size_t vbase = ((((size_t)b) * 12 + h) << 16);
  const size_t bbase = (((size_t)h) << 20) + ((size_t)n0 << 10);
  const float tmp = temp[h];
  const int rowl = wid*16 + lq*4;

#pragma unroll
  for (int it = 0; it < 2; ++it) {    // q tile once
    int c = it*256 + tid; int ks = c >> 8, r = (c >> 2) & 63, c8 = c & 3;
    gl2lds16(q + qbase + (size_t)r * 64 + ks*32 + c8*8, (char*)qt + (it*256 + wid*64) * 16);
  }
  for (int i = tid; i < 1024; i += 256) {  // ones-column rows (persist across tiles)
    int ks = i >> 9, rr = (i >> 5) & 15, cc = i & 31;
    vt[ks*2560 + (64 + rr)*32 + cc] = (rr == 0) ? (u16)0x3F80 : (u16)0;
  }
  f32x4 oacc[5] = {};   // [0..3]=O cols, [4]=l (ones column)

  for (int m0 = 0; m0 < 1024; m0 += 64) {
#pragma unroll
    for (int it = 0; it < 2; ++it) {
      int c = it*256 + tid; int ks = c >> 8, r = (c >> 2) & 63, c8 = c & 3;
      gl2lds16(k  + kbase + (size_t)(m0 + r) * 64 + ks*32 + c8*8, (char*)kt + (it*256 + wid*64) * 16);
      gl2lds16(vT + vbase + (size_t)r * 1024 + m0 + ks*32 + c8*8, (char*)vt + it*5120 + wid*1024);
    }
    float breg[4][4];
#pragma unroll
    for (int r = 0; r < 4; ++r)
#pragma unroll
      for (int nj = 0; nj < 4; ++nj)
        breg[r][nj] = bias[bbase + (size_t)(rowl + r) * 1024 + m0 + nj*16 + lr];
    __syncthreads();
    f32x4 s[4] = {};
#pragma unroll
    for (int ks = 0; ks < 2; ++ks) {
      bf16x8 aq = *(const bf16x8*)&qt[ks*2048 + (wid*16 + lr)*32 + lq*8];
#pragma unroll
      for (int nj = 0; nj < 4; ++nj) {
        bf16x8 bk = *(const bf16x8*)&kt[ks*2048 + (nj*16 + lr)*32 + lq*8];
        s[nj] = __builtin_amdgcn_mfma_f32_16x16x32_bf16(aq, bk, s[nj], 0, 0, 0);
      }
    }
#pragma unroll
    for (int r = 0; r < 4; ++r)
#pragma unroll
      for (int nj = 0; nj < 4; ++nj) {
        float pv = __expf((s[nj][r] + breg[r][nj]) * tmp);
        pt[(rowl + r)*72 + nj*16 + lr] = f2b(pv);
      }
#pragma unroll
    for (int ks = 0; ks < 2; ++ks) {
      bf16x8 ap = *(const bf16x8*)&pt[(wid*16 + lr)*72 + ks*32 + lq*8];
#pragma unroll
      for (int dj = 0; dj < 5; ++dj) {
        bf16x8 bv = *(const bf16x8*)&vt[ks*2560 + (dj*16 + lr)*32 + lq*8];
        oacc[dj] = __builtin_amdgcn_mfma_f32_16x16x32_bf16(ap, bv, oacc[dj], 0, 0, 0);
      }
    }
    __syncthreads();
  }
#pragma unroll
  for (int r = 0; r < 4; ++r) {
    float l = __shfl(oacc[4][r], lane & 48);
    float linv = 1.f / l;
    int n = n0 + rowl + r;
#pragma unroll
    for (int dj = 0; dj < 4; ++dj) {
      int col = h*64 + dj*16 + lr;
      out[((size_t)(b*1024 + n)) * 768 + col] = f2b(oacc[dj][r] * linv);
    }
  }
}

// ---------------------------------------------------------------- K7: out = attn @ w_proj^T + b_proj (fp32 out)
__global__ __launch_bounds__(256) void proj_gemm(
    const u16* __restrict__ A, const u16* __restrict__ W,
    const float* __restrict__ bp, float* __restrict__ out)
{
  __shared__ u16 As[128*32];
  __shared__ u16 Bs[128*32];
  const int tid = threadIdx.x, lane = tid & 63, wid = tid >> 6;
  const int m0 = blockIdx.y * 128, n0 = blockIdx.x * 128;
  const int wm = (wid >> 1) * 64, wn = (wid & 1) * 64;
  const int lr = lane & 15, lq = lane >> 4;
  f32x4 acc[4][4] = {};
  for (int k0 = 0; k0 < 768; k0 += 32) {
#pragma unroll
    for (int it = 0; it < 2; ++it) {
      int c = it*256 + tid; int row = c >> 2, c8 = c & 3;
      gl2lds16(A + (size_t)(m0 + row) * 768 + k0 + c8*8, (char*)As + (it*256 + wid*64) * 16);
      gl2lds16(W + (size_t)(n0 + row) * 768 + k0 + c8*8, (char*)Bs + (it*256 + wid*64) * 16);
    }
    __syncthreads();
    bf16x8 af[4], bfr[4];
#pragma unroll
    for (int i = 0; i < 4; ++i) {
      af[i]  = *(const bf16x8*)&As[(wm + i*16 + lr)*32 + lq*8];
      bfr[i] = *(const bf16x8*)&Bs[(wn + i*16 + lr)*32 + lq*8];
    }
#pragma unroll
    for (int mi = 0; mi < 4; ++mi)
#pragma unroll
      for (int nj = 0; nj < 4; ++nj)
        acc[mi][nj] = __builtin_amdgcn_mfma_f32_16x16x32_bf16(af[mi], bfr[nj], acc[mi][nj], 0, 0, 0);
    __syncthreads();
  }
#pragma unroll
  for (int mi = 0; mi < 4; ++mi)
#pragma unroll
    for (int nj = 0; nj < 4; ++nj)
#pragma unroll
      for (int r = 0; r < 4; ++r) {
        int row = m0 + wm + mi*16 + lq*4 + r;
        int col = n0 + wn + nj*16 + lr;
        out[(size_t)row * 768 + col] = acc[mi][nj][r] + bp[col];
      }
}

// ----------------------------------------------------------------
extern "C" void kernel_launch(void* const* d_in, const int* in_sizes, int n_in,
                              void* d_out, int out_size, void* d_ws, size_t ws_size,
                              hipStream_t stream)
{
  const float* x     = (const float*)d_in[0];
  const float* wqv   = (const float*)d_in[1];
  const float* ek    = (const float*)d_in[2];
  const float* ebias = (const float*)d_in[3];
  const float* gamma = (const float*)d_in[4];
  // d_in[5] = bn_beta: cancels inside softmax (per-row constant) — unused.
  const float* wp    = (const float*)d_in[6];
  const float* bp    = (const float*)d_in[7];
  float* out = (float*)d_out;

  char* ws = (char*)d_ws;
  size_t off = 0;
  auto alloc = [&](size_t bytes) { char* p = ws + off; off += (bytes + 255) & ~(size_t)255; return p; };
  u16* x16   = (u16*)alloc((size_t)8192*768*2);   // also reused: gram partials, attn output
  u16* wqv16 = (u16*)alloc((size_t)1536*768*2);
  u16* wp16  = (u16*)alloc((size_t)768*768*2);
  u16* k16   = (u16*)alloc((size_t)12*1024*64*2);
  u16* ktT16 = (u16*)alloc((size_t)12*64*1024*2);
  u16* q16   = (u16*)alloc((size_t)8*12*1024*64*2);
  u16* v16   = (u16*)alloc((size_t)8*12*1024*64*2);
  u16* vt16  = (u16*)alloc((size_t)8*12*1024*64*2);
  float* qs  = (float*)alloc((size_t)12*1024*64*4);
  float* acc = (float*)alloc(3*12*4);          // zero region start
  float* qsum = (float*)alloc(12*64*4);
  float* ksum = (float*)alloc(12*64*4);
  size_t zbytes = (size_t)(((char*)ksum + 12*64*4) - (char*)acc);
  float* temp = (float*)alloc(12*4);
  // Gram partials overlaid on x16 (dead after qv_gemm; partials dead after finalize)
  float* Qgp = (float*)x16;                    // 32*12*4096 f32 = 6.29 MB
  float* Kgp = Qgp + (size_t)GQ_*12*4096;      //  4*12*4096 f32 = 0.79 MB
  u16* attn16 = x16;                           // attn output reuses x16 after finalize

  hipMemsetAsync(acc, 0, zbytes, stream);

  { // K0: casts (x, w_qv, w_proj, ext_k)
    int c0 = 8192*768/4, c1 = 1536*768/4, c2 = 768*768/4, c3 = 12*1024*64/4;
    int total = c0 + c1 + c2 + c3;
    cast_all<<<(total + 255)/256, 256, 0, stream>>>(
        (const float4*)x, x16, c0, (const float4*)wqv, wqv16, c1,
        (const float4*)wp, wp16, c2, (const float4*)ek, k16, c3);
  }
  qv_gemm<<<dim3(12, 64), 256, 0, stream>>>(x16, wqv16, q16, v16);
  transpose_v<<<dim3(16, 108), 256, 0, stream>>>(v16, vt16, k16, ktT16);
  qs_kernel<<<3072, 256, 0, stream>>>(q16, qs);
  gram_kernel<<<dim3(GK_, 12), 256, 0, stream>>>(k16, Kgp, 1024/GK_, 0);
  gram_kernel<<<dim3(GQ_, 12), 256, 0, stream>>>(q16, Qgp, 8192/GQ_, 1);
  bias_stats<<<dim3(64, 12), 256, 0, stream>>>(ebias, ktT16, qs, acc);
  sums_kernel<<<dim3(12, 9), 256, 0, stream>>>(qs, k16, qsum, ksum);
  finalize_kernel<<<12, 256, 0, stream>>>(qsum, ksum, Qgp, Kgp, acc, gamma, temp);
  attn_kernel<<<dim3(1536), 256, 0, stream>>>(q16, k16, vt16, ebias, temp, attn16);
  proj_gemm<<<dim3(6, 64), 256, 0, stream>>>(attn16, wp16, bp, out);
}